// Round 1
// baseline (1659.041 us; speedup 1.0000x reference)
//
#include <hip/hip_runtime.h>
#include <cstddef>

// GIN forward on MI355X — round 1: fp32 correctness baseline.
// Structure: CSR build (once/call) -> per layer {gather, GEMM1(fused (1+eps)x+agg, relu),
// GEMM2(relu), col-stats, BN(+residual)} -> final GEMM(tanh + atomic mean-pool).

namespace {
constexpr int kN = 50000;
constexpr int kE = 800000;
constexpr int kH = 128;
constexpr int kL = 5;
constexpr int kG = 64;
constexpr float kBnEps = 1e-5f;
}

// ---------------- graph build (once per call) ----------------

__global__ void hist_kernel(const int* __restrict__ dst, int* __restrict__ deg) {
    int i = blockIdx.x * blockDim.x + threadIdx.x;
    if (i < kE) atomicAdd(&deg[dst[i]], 1);
}

// single-block exclusive scan over deg[kN]; writes rowptr[kN+1] and resets deg -> cursor
__global__ void scan_kernel(int* __restrict__ deg, int* __restrict__ rowptr) {
    __shared__ int lds[1024];
    const int tid = threadIdx.x;
    const int chunk = (kN + 1023) >> 10;  // 49
    int start = tid * chunk; if (start > kN) start = kN;
    int end = start + chunk; if (end > kN) end = kN;
    int s = 0;
    for (int i = start; i < end; ++i) s += deg[i];
    lds[tid] = s;
    __syncthreads();
    for (int d = 1; d < 1024; d <<= 1) {
        int v = lds[tid];
        if (tid >= d) v += lds[tid - d];
        __syncthreads();
        lds[tid] = v;
        __syncthreads();
    }
    int off = (tid == 0) ? 0 : lds[tid - 1];
    for (int i = start; i < end; ++i) {
        int dv = deg[i];
        rowptr[i] = off;
        deg[i] = off;  // cursor init for scatter
        off += dv;
    }
    if (tid == 1023) rowptr[kN] = off;  // == kE
}

__global__ void scatter_kernel(const int* __restrict__ src, const int* __restrict__ dst,
                               int* __restrict__ cursor, int* __restrict__ col) {
    int i = blockIdx.x * blockDim.x + threadIdx.x;
    if (i < kE) {
        int p = atomicAdd(&cursor[dst[i]], 1);
        col[p] = src[i];
    }
}

__global__ void count_kernel(const int* __restrict__ batch, float* __restrict__ cnt) {
    int i = blockIdx.x * blockDim.x + threadIdx.x;
    if (i < kN) atomicAdd(&cnt[batch[i]], 1.0f);
}

// ---------------- aggregation: agg[n] = sum_{j in N(n)} h[col[j]] ----------------
// one wave per node, float2 per lane (64 lanes * 8B = full 512B row, coalesced)
__global__ __launch_bounds__(256) void gather_kernel(const float* __restrict__ h,
                                                     const int* __restrict__ rowptr,
                                                     const int* __restrict__ col,
                                                     float* __restrict__ agg) {
    const int lane = threadIdx.x & 63;
    const int n = blockIdx.x * 4 + (threadIdx.x >> 6);
    if (n >= kN) return;
    const int e0 = rowptr[n], e1 = rowptr[n + 1];
    float ax = 0.f, ay = 0.f;
    const float2* hp = reinterpret_cast<const float2*>(h);
    for (int e = e0; e < e1; ++e) {
        int s = col[e];
        float2 v = hp[(size_t)s * 64 + lane];
        ax += v.x;
        ay += v.y;
    }
    reinterpret_cast<float2*>(agg)[(size_t)n * 64 + lane] = make_float2(ax, ay);
}

// ---------------- GEMM: [64 rows x 128 cols] per 256-thread block ----------------
// MODE 0: A = (1+eps)*A0 + A1, epilogue relu->out
// MODE 1: A = A0,              epilogue relu->out
// MODE 2: A = A0,              epilogue tanh + atomicAdd pooled[batch[row]]
template <int MODE>
__global__ __launch_bounds__(256, 2) void gemm_kernel(
    const float* __restrict__ A0, const float* __restrict__ A1,
    const float* __restrict__ W, const float* __restrict__ bias,
    const float* __restrict__ eps_p, int layer,
    float* __restrict__ out,
    const int* __restrict__ batch, float* __restrict__ pooled) {
    __shared__ float As[64][kH];   // 32 KB
    __shared__ float Ws[64][kH];   // 32 KB (half of W at a time)
    const int tid = threadIdx.x;
    const int tx = tid & 31;   // 4 cols each: c0 = 4*tx
    const int ty = tid >> 5;   // 8 rows each: r0 = 8*ty
    const int row0 = blockIdx.x * 64;

    float scale = 1.0f;
    if (MODE == 0) scale = 1.0f + eps_p[layer];

    // stage A tile (row-major, conflict-free float4 writes)
#pragma unroll
    for (int p = 0; p < 8; ++p) {
        int idx = tid + p * 256;
        int r = idx >> 5;
        int f = idx & 31;
        int row = row0 + r;
        float4 v = make_float4(0.f, 0.f, 0.f, 0.f);
        if (row < kN) {
            v = reinterpret_cast<const float4*>(A0 + (size_t)row * kH)[f];
            if (MODE == 0) {
                float4 u = reinterpret_cast<const float4*>(A1 + (size_t)row * kH)[f];
                v.x = scale * v.x + u.x;
                v.y = scale * v.y + u.y;
                v.z = scale * v.z + u.z;
                v.w = scale * v.w + u.w;
            }
        }
        *reinterpret_cast<float4*>(&As[r][f * 4]) = v;
    }

    float acc[8][4];
#pragma unroll
    for (int i = 0; i < 8; ++i)
#pragma unroll
        for (int j = 0; j < 4; ++j) acc[i][j] = 0.f;

    for (int half = 0; half < 2; ++half) {
        __syncthreads();  // As ready (half 0) / prev half's reads done
#pragma unroll
        for (int p = 0; p < 8; ++p) {
            int idx = tid + p * 256;
            int k = idx >> 5;
            int f = idx & 31;
            *reinterpret_cast<float4*>(&Ws[k][f * 4]) =
                reinterpret_cast<const float4*>(W + (size_t)(half * 64 + k) * kH)[f];
        }
        __syncthreads();
#pragma unroll 2
        for (int k0 = 0; k0 < 64; k0 += 4) {
            float4 w[4];
#pragma unroll
            for (int j = 0; j < 4; ++j)
                w[j] = *reinterpret_cast<const float4*>(&Ws[k0 + j][tx * 4]);
            float4 a[8];
#pragma unroll
            for (int i = 0; i < 8; ++i)
                a[i] = *reinterpret_cast<const float4*>(&As[ty * 8 + i][half * 64 + k0]);
#pragma unroll
            for (int i = 0; i < 8; ++i) {
                acc[i][0] += a[i].x * w[0].x; acc[i][1] += a[i].x * w[0].y;
                acc[i][2] += a[i].x * w[0].z; acc[i][3] += a[i].x * w[0].w;
                acc[i][0] += a[i].y * w[1].x; acc[i][1] += a[i].y * w[1].y;
                acc[i][2] += a[i].y * w[1].z; acc[i][3] += a[i].y * w[1].w;
                acc[i][0] += a[i].z * w[2].x; acc[i][1] += a[i].z * w[2].y;
                acc[i][2] += a[i].z * w[2].z; acc[i][3] += a[i].z * w[2].w;
                acc[i][0] += a[i].w * w[3].x; acc[i][1] += a[i].w * w[3].y;
                acc[i][2] += a[i].w * w[3].z; acc[i][3] += a[i].w * w[3].w;
            }
        }
    }

    const int c0 = tx * 4;
    float4 b4 = *reinterpret_cast<const float4*>(bias + c0);
#pragma unroll
    for (int i = 0; i < 8; ++i) {
        int row = row0 + ty * 8 + i;
        if (row >= kN) break;
        float o0 = acc[i][0] + b4.x;
        float o1 = acc[i][1] + b4.y;
        float o2 = acc[i][2] + b4.z;
        float o3 = acc[i][3] + b4.w;
        if (MODE < 2) {
            float4 o = make_float4(fmaxf(o0, 0.f), fmaxf(o1, 0.f), fmaxf(o2, 0.f), fmaxf(o3, 0.f));
            *reinterpret_cast<float4*>(out + (size_t)row * kH + c0) = o;
        } else {
            int g = batch[row];
            float* pp = pooled + (size_t)g * kH + c0;
            atomicAdd(pp + 0, tanhf(o0));
            atomicAdd(pp + 1, tanhf(o1));
            atomicAdd(pp + 2, tanhf(o2));
            atomicAdd(pp + 3, tanhf(o3));
        }
    }
}

// ---------------- per-column sums / sums-of-squares ----------------
__global__ __launch_bounds__(256) void stats_kernel(const float* __restrict__ h,
                                                    float* __restrict__ sums,
                                                    float* __restrict__ sumsq) {
    __shared__ float ls[2][kH], lq[2][kH];
    const int tid = threadIdx.x;
    const int c = tid & 127;
    const int y = tid >> 7;
    float s = 0.f, q = 0.f;
    for (int r = blockIdx.x * 2 + y; r < kN; r += gridDim.x * 2) {
        float v = h[(size_t)r * kH + c];
        s += v;
        q += v * v;
    }
    ls[y][c] = s;
    lq[y][c] = q;
    __syncthreads();
    if (y == 0) {
        atomicAdd(&sums[c], ls[0][c] + ls[1][c]);
        atomicAdd(&sumsq[c], lq[0][c] + lq[1][c]);
    }
}

// ---------------- BN (+ optional relu + residual) ----------------
__global__ __launch_bounds__(256) void bn_kernel(const float* __restrict__ h2,
                                                 float* __restrict__ hcur,
                                                 const float* __restrict__ gamma,
                                                 const float* __restrict__ beta,
                                                 const float* __restrict__ sums,
                                                 const float* __restrict__ sumsq,
                                                 int first) {
    const float invN = 1.0f / (float)kN;
    const size_t total = (size_t)kN * (kH / 4);
    const size_t stride = (size_t)gridDim.x * blockDim.x;
    for (size_t i = (size_t)blockIdx.x * blockDim.x + threadIdx.x; i < total; i += stride) {
        int c0 = ((int)(i & 31)) * 4;
        float4 s4 = *reinterpret_cast<const float4*>(sums + c0);
        float4 q4 = *reinterpret_cast<const float4*>(sumsq + c0);
        float4 g4 = *reinterpret_cast<const float4*>(gamma + c0);
        float4 be4 = *reinterpret_cast<const float4*>(beta + c0);
        float4 h4 = reinterpret_cast<const float4*>(h2)[i];
        float o0, o1, o2, o3;
        {
            float mu = s4.x * invN, var = fmaxf(q4.x * invN - mu * mu, 0.f);
            o0 = (h4.x - mu) * rsqrtf(var + kBnEps) * g4.x + be4.x;
        }
        {
            float mu = s4.y * invN, var = fmaxf(q4.y * invN - mu * mu, 0.f);
            o1 = (h4.y - mu) * rsqrtf(var + kBnEps) * g4.y + be4.y;
        }
        {
            float mu = s4.z * invN, var = fmaxf(q4.z * invN - mu * mu, 0.f);
            o2 = (h4.z - mu) * rsqrtf(var + kBnEps) * g4.z + be4.z;
        }
        {
            float mu = s4.w * invN, var = fmaxf(q4.w * invN - mu * mu, 0.f);
            o3 = (h4.w - mu) * rsqrtf(var + kBnEps) * g4.w + be4.w;
        }
        if (first) {
            reinterpret_cast<float4*>(hcur)[i] = make_float4(o0, o1, o2, o3);
        } else {
            float4 p = reinterpret_cast<float4*>(hcur)[i];
            p.x += fmaxf(o0, 0.f);
            p.y += fmaxf(o1, 0.f);
            p.z += fmaxf(o2, 0.f);
            p.w += fmaxf(o3, 0.f);
            reinterpret_cast<float4*>(hcur)[i] = p;
        }
    }
}

__global__ void div_kernel(const float* __restrict__ pooled, const float* __restrict__ cnt,
                           float* __restrict__ out) {
    int i = blockIdx.x * blockDim.x + threadIdx.x;
    if (i < kG * kH) out[i] = pooled[i] / fmaxf(cnt[i >> 7], 1.0f);
}

// ---------------- launch ----------------
extern "C" void kernel_launch(void* const* d_in, const int* in_sizes, int n_in,
                              void* d_out, int out_size, void* d_ws, size_t ws_size,
                              hipStream_t stream) {
    const float* x     = (const float*)d_in[0];
    const int*   ei    = (const int*)d_in[1];
    const int*   batch = (const int*)d_in[2];
    const float* W1    = (const float*)d_in[3];
    const float* b1    = (const float*)d_in[4];
    const float* W2    = (const float*)d_in[5];
    const float* b2    = (const float*)d_in[6];
    const float* gamma = (const float*)d_in[7];
    const float* beta  = (const float*)d_in[8];
    const float* eps   = (const float*)d_in[9];
    const float* linW  = (const float*)d_in[10];
    const float* linb  = (const float*)d_in[11];
    float* out = (float*)d_out;

    char* ws = (char*)d_ws;
    size_t off = 0;
    auto alloc = [&](size_t bytes) -> char* {
        char* p = ws + off;
        off = (off + bytes + 15) & ~(size_t)15;
        return p;
    };
    float* agg    = (float*)alloc((size_t)kN * kH * 4);  // also holds h2 after GEMM2
    float* hcur   = (float*)alloc((size_t)kN * kH * 4);
    float* hmid   = (float*)alloc((size_t)kN * kH * 4);
    int*   rowptr = (int*)alloc((size_t)(kN + 1) * 4);
    int*   cursor = (int*)alloc((size_t)kN * 4);         // deg, then cursor
    int*   colidx = (int*)alloc((size_t)kE * 4);
    float* stats  = (float*)alloc((size_t)kL * 256 * 4); // per layer: [sums 128][sumsq 128]
    float* pooled = (float*)alloc((size_t)(kG * kH + kG) * 4);
    float* cnt    = pooled + kG * kH;

    const int* srcp = ei;       // edge_index[0] (source)
    const int* dstp = ei + kE;  // edge_index[1] (target)

    hipMemsetAsync(cursor, 0, (size_t)kN * 4, stream);
    hipMemsetAsync(stats, 0, (size_t)kL * 256 * 4, stream);
    hipMemsetAsync(pooled, 0, (size_t)(kG * kH + kG) * 4, stream);

    hist_kernel<<<(kE + 255) / 256, 256, 0, stream>>>(dstp, cursor);
    scan_kernel<<<1, 1024, 0, stream>>>(cursor, rowptr);
    scatter_kernel<<<(kE + 255) / 256, 256, 0, stream>>>(srcp, dstp, cursor, colidx);
    count_kernel<<<(kN + 255) / 256, 256, 0, stream>>>(batch, cnt);

    const int gemm_grid = (kN + 63) / 64;
    for (int l = 0; l < kL; ++l) {
        const float* hin = (l == 0) ? x : hcur;
        gather_kernel<<<(kN + 3) / 4, 256, 0, stream>>>(hin, rowptr, colidx, agg);
        gemm_kernel<0><<<gemm_grid, 256, 0, stream>>>(
            hin, agg, W1 + (size_t)l * kH * kH, b1 + (size_t)l * kH, eps, l, hmid, nullptr,
            nullptr);
        gemm_kernel<1><<<gemm_grid, 256, 0, stream>>>(
            hmid, nullptr, W2 + (size_t)l * kH * kH, b2 + (size_t)l * kH, nullptr, 0, agg,
            nullptr, nullptr);
        stats_kernel<<<512, 256, 0, stream>>>(agg, stats + l * 256, stats + l * 256 + 128);
        bn_kernel<<<2048, 256, 0, stream>>>(agg, hcur, gamma + (size_t)l * kH,
                                            beta + (size_t)l * kH, stats + l * 256,
                                            stats + l * 256 + 128, l == 0 ? 1 : 0);
    }
    gemm_kernel<2><<<gemm_grid, 256, 0, stream>>>(hcur, nullptr, linW, linb, nullptr, 0, nullptr,
                                                  batch, pooled);
    div_kernel<<<(kG * kH + 255) / 256, 256, 0, stream>>>(pooled, cnt, out);
}

// Round 2
// 1419.820 us; speedup vs baseline: 1.1685x; 1.1685x over previous
//
#include <hip/hip_runtime.h>
#include <cstddef>

// GIN forward on MI355X — round 2: kill atomic pooling (was 307us, 131MB HBM RMW writes).
// batch is sorted -> segment pooling: MODE2 GEMM does plain tanh stores, then a
// 64-block segment-sum kernel. Everything else unchanged from the passing R1 baseline.

namespace {
constexpr int kN = 50000;
constexpr int kE = 800000;
constexpr int kH = 128;
constexpr int kL = 5;
constexpr int kG = 64;
constexpr float kBnEps = 1e-5f;
}

// ---------------- graph build (once per call) ----------------

__global__ void hist_kernel(const int* __restrict__ dst, int* __restrict__ deg) {
    int i = blockIdx.x * blockDim.x + threadIdx.x;
    if (i < kE) atomicAdd(&deg[dst[i]], 1);
}

// single-block exclusive scan over deg[kN]; writes rowptr[kN+1] and resets deg -> cursor
__global__ void scan_kernel(int* __restrict__ deg, int* __restrict__ rowptr) {
    __shared__ int lds[1024];
    const int tid = threadIdx.x;
    const int chunk = (kN + 1023) >> 10;  // 49
    int start = tid * chunk; if (start > kN) start = kN;
    int end = start + chunk; if (end > kN) end = kN;
    int s = 0;
    for (int i = start; i < end; ++i) s += deg[i];
    lds[tid] = s;
    __syncthreads();
    for (int d = 1; d < 1024; d <<= 1) {
        int v = lds[tid];
        if (tid >= d) v += lds[tid - d];
        __syncthreads();
        lds[tid] = v;
        __syncthreads();
    }
    int off = (tid == 0) ? 0 : lds[tid - 1];
    for (int i = start; i < end; ++i) {
        int dv = deg[i];
        rowptr[i] = off;
        deg[i] = off;  // cursor init for scatter
        off += dv;
    }
    if (tid == 1023) rowptr[kN] = off;  // == kE
}

__global__ void scatter_kernel(const int* __restrict__ src, const int* __restrict__ dst,
                               int* __restrict__ cursor, int* __restrict__ col) {
    int i = blockIdx.x * blockDim.x + threadIdx.x;
    if (i < kE) {
        int p = atomicAdd(&cursor[dst[i]], 1);
        col[p] = src[i];
    }
}

__global__ void count_kernel(const int* __restrict__ batch, int* __restrict__ gcnt) {
    int i = blockIdx.x * blockDim.x + threadIdx.x;
    if (i < kN) atomicAdd(&gcnt[batch[i]], 1);
}

// inclusive scan over 64 graph counts -> gp[65] (one wave)
__global__ void gprefix_kernel(const int* __restrict__ gcnt, int* __restrict__ gp) {
    int lane = threadIdx.x;  // 64 threads = 1 wave
    int s = gcnt[lane];
    for (int d = 1; d < 64; d <<= 1) {
        int t = __shfl_up(s, d);
        if (lane >= d) s += t;
    }
    gp[lane + 1] = s;
    if (lane == 0) gp[0] = 0;
}

// ---------------- aggregation: agg[n] = sum_{j in N(n)} h[col[j]] ----------------
__global__ __launch_bounds__(256) void gather_kernel(const float* __restrict__ h,
                                                     const int* __restrict__ rowptr,
                                                     const int* __restrict__ col,
                                                     float* __restrict__ agg) {
    const int lane = threadIdx.x & 63;
    const int n = blockIdx.x * 4 + (threadIdx.x >> 6);
    if (n >= kN) return;
    const int e0 = rowptr[n], e1 = rowptr[n + 1];
    float ax = 0.f, ay = 0.f;
    const float2* hp = reinterpret_cast<const float2*>(h);
    for (int e = e0; e < e1; ++e) {
        int s = col[e];
        float2 v = hp[(size_t)s * 64 + lane];
        ax += v.x;
        ay += v.y;
    }
    reinterpret_cast<float2*>(agg)[(size_t)n * 64 + lane] = make_float2(ax, ay);
}

// ---------------- GEMM: [64 rows x 128 cols] per 256-thread block ----------------
// MODE 0: A = (1+eps)*A0 + A1, epilogue relu->out
// MODE 1: A = A0,              epilogue relu->out
// MODE 2: A = A0,              epilogue tanh->out (plain stores; pooling is separate)
template <int MODE>
__global__ __launch_bounds__(256, 2) void gemm_kernel(
    const float* __restrict__ A0, const float* __restrict__ A1,
    const float* __restrict__ W, const float* __restrict__ bias,
    const float* __restrict__ eps_p, int layer,
    float* __restrict__ out) {
    __shared__ float As[64][kH];   // 32 KB
    __shared__ float Ws[64][kH];   // 32 KB (half of W at a time)
    const int tid = threadIdx.x;
    const int tx = tid & 31;   // 4 cols each: c0 = 4*tx
    const int ty = tid >> 5;   // 8 rows each: r0 = 8*ty
    const int row0 = blockIdx.x * 64;

    float scale = 1.0f;
    if (MODE == 0) scale = 1.0f + eps_p[layer];

#pragma unroll
    for (int p = 0; p < 8; ++p) {
        int idx = tid + p * 256;
        int r = idx >> 5;
        int f = idx & 31;
        int row = row0 + r;
        float4 v = make_float4(0.f, 0.f, 0.f, 0.f);
        if (row < kN) {
            v = reinterpret_cast<const float4*>(A0 + (size_t)row * kH)[f];
            if (MODE == 0) {
                float4 u = reinterpret_cast<const float4*>(A1 + (size_t)row * kH)[f];
                v.x = scale * v.x + u.x;
                v.y = scale * v.y + u.y;
                v.z = scale * v.z + u.z;
                v.w = scale * v.w + u.w;
            }
        }
        *reinterpret_cast<float4*>(&As[r][f * 4]) = v;
    }

    float acc[8][4];
#pragma unroll
    for (int i = 0; i < 8; ++i)
#pragma unroll
        for (int j = 0; j < 4; ++j) acc[i][j] = 0.f;

    for (int half = 0; half < 2; ++half) {
        __syncthreads();
#pragma unroll
        for (int p = 0; p < 8; ++p) {
            int idx = tid + p * 256;
            int k = idx >> 5;
            int f = idx & 31;
            *reinterpret_cast<float4*>(&Ws[k][f * 4]) =
                reinterpret_cast<const float4*>(W + (size_t)(half * 64 + k) * kH)[f];
        }
        __syncthreads();
#pragma unroll 2
        for (int k0 = 0; k0 < 64; k0 += 4) {
            float4 w[4];
#pragma unroll
            for (int j = 0; j < 4; ++j)
                w[j] = *reinterpret_cast<const float4*>(&Ws[k0 + j][tx * 4]);
            float4 a[8];
#pragma unroll
            for (int i = 0; i < 8; ++i)
                a[i] = *reinterpret_cast<const float4*>(&As[ty * 8 + i][half * 64 + k0]);
#pragma unroll
            for (int i = 0; i < 8; ++i) {
                acc[i][0] += a[i].x * w[0].x; acc[i][1] += a[i].x * w[0].y;
                acc[i][2] += a[i].x * w[0].z; acc[i][3] += a[i].x * w[0].w;
                acc[i][0] += a[i].y * w[1].x; acc[i][1] += a[i].y * w[1].y;
                acc[i][2] += a[i].y * w[1].z; acc[i][3] += a[i].y * w[1].w;
                acc[i][0] += a[i].z * w[2].x; acc[i][1] += a[i].z * w[2].y;
                acc[i][2] += a[i].z * w[2].z; acc[i][3] += a[i].z * w[2].w;
                acc[i][0] += a[i].w * w[3].x; acc[i][1] += a[i].w * w[3].y;
                acc[i][2] += a[i].w * w[3].z; acc[i][3] += a[i].w * w[3].w;
            }
        }
    }

    const int c0 = tx * 4;
    float4 b4 = *reinterpret_cast<const float4*>(bias + c0);
#pragma unroll
    for (int i = 0; i < 8; ++i) {
        int row = row0 + ty * 8 + i;
        if (row >= kN) break;
        float o0 = acc[i][0] + b4.x;
        float o1 = acc[i][1] + b4.y;
        float o2 = acc[i][2] + b4.z;
        float o3 = acc[i][3] + b4.w;
        float4 o;
        if (MODE < 2) {
            o = make_float4(fmaxf(o0, 0.f), fmaxf(o1, 0.f), fmaxf(o2, 0.f), fmaxf(o3, 0.f));
        } else {
            o = make_float4(tanhf(o0), tanhf(o1), tanhf(o2), tanhf(o3));
        }
        *reinterpret_cast<float4*>(out + (size_t)row * kH + c0) = o;
    }
}

// ---------------- segment mean pool: out[g] = mean over rows gp[g]..gp[g+1] ----------------
__global__ __launch_bounds__(512) void pool_kernel(const float* __restrict__ y,
                                                   const int* __restrict__ gp,
                                                   float* __restrict__ out) {
    __shared__ float part[4][kH];
    const int g = blockIdx.x;
    const int c = threadIdx.x & 127;
    const int q = threadIdx.x >> 7;  // 0..3
    const int s = gp[g], e = gp[g + 1];
    float acc = 0.f;
    for (int r = s + q; r < e; r += 4) acc += y[(size_t)r * kH + c];
    part[q][c] = acc;
    __syncthreads();
    if (q == 0) {
        float v = part[0][c] + part[1][c] + part[2][c] + part[3][c];
        out[g * kH + c] = v / fmaxf((float)(e - s), 1.0f);
    }
}

// ---------------- per-column sums / sums-of-squares ----------------
__global__ __launch_bounds__(256) void stats_kernel(const float* __restrict__ h,
                                                    float* __restrict__ sums,
                                                    float* __restrict__ sumsq) {
    __shared__ float ls[2][kH], lq[2][kH];
    const int tid = threadIdx.x;
    const int c = tid & 127;
    const int y = tid >> 7;
    float s = 0.f, q = 0.f;
    for (int r = blockIdx.x * 2 + y; r < kN; r += gridDim.x * 2) {
        float v = h[(size_t)r * kH + c];
        s += v;
        q += v * v;
    }
    ls[y][c] = s;
    lq[y][c] = q;
    __syncthreads();
    if (y == 0) {
        atomicAdd(&sums[c], ls[0][c] + ls[1][c]);
        atomicAdd(&sumsq[c], lq[0][c] + lq[1][c]);
    }
}

// ---------------- BN (+ optional relu + residual) ----------------
__global__ __launch_bounds__(256) void bn_kernel(const float* __restrict__ h2,
                                                 float* __restrict__ hcur,
                                                 const float* __restrict__ gamma,
                                                 const float* __restrict__ beta,
                                                 const float* __restrict__ sums,
                                                 const float* __restrict__ sumsq,
                                                 int first) {
    const float invN = 1.0f / (float)kN;
    const size_t total = (size_t)kN * (kH / 4);
    const size_t stride = (size_t)gridDim.x * blockDim.x;
    for (size_t i = (size_t)blockIdx.x * blockDim.x + threadIdx.x; i < total; i += stride) {
        int c0 = ((int)(i & 31)) * 4;
        float4 s4 = *reinterpret_cast<const float4*>(sums + c0);
        float4 q4 = *reinterpret_cast<const float4*>(sumsq + c0);
        float4 g4 = *reinterpret_cast<const float4*>(gamma + c0);
        float4 be4 = *reinterpret_cast<const float4*>(beta + c0);
        float4 h4 = reinterpret_cast<const float4*>(h2)[i];
        float o0, o1, o2, o3;
        {
            float mu = s4.x * invN, var = fmaxf(q4.x * invN - mu * mu, 0.f);
            o0 = (h4.x - mu) * rsqrtf(var + kBnEps) * g4.x + be4.x;
        }
        {
            float mu = s4.y * invN, var = fmaxf(q4.y * invN - mu * mu, 0.f);
            o1 = (h4.y - mu) * rsqrtf(var + kBnEps) * g4.y + be4.y;
        }
        {
            float mu = s4.z * invN, var = fmaxf(q4.z * invN - mu * mu, 0.f);
            o2 = (h4.z - mu) * rsqrtf(var + kBnEps) * g4.z + be4.z;
        }
        {
            float mu = s4.w * invN, var = fmaxf(q4.w * invN - mu * mu, 0.f);
            o3 = (h4.w - mu) * rsqrtf(var + kBnEps) * g4.w + be4.w;
        }
        if (first) {
            reinterpret_cast<float4*>(hcur)[i] = make_float4(o0, o1, o2, o3);
        } else {
            float4 p = reinterpret_cast<float4*>(hcur)[i];
            p.x += fmaxf(o0, 0.f);
            p.y += fmaxf(o1, 0.f);
            p.z += fmaxf(o2, 0.f);
            p.w += fmaxf(o3, 0.f);
            reinterpret_cast<float4*>(hcur)[i] = p;
        }
    }
}

// ---------------- launch ----------------
extern "C" void kernel_launch(void* const* d_in, const int* in_sizes, int n_in,
                              void* d_out, int out_size, void* d_ws, size_t ws_size,
                              hipStream_t stream) {
    const float* x     = (const float*)d_in[0];
    const int*   ei    = (const int*)d_in[1];
    const int*   batch = (const int*)d_in[2];
    const float* W1    = (const float*)d_in[3];
    const float* b1    = (const float*)d_in[4];
    const float* W2    = (const float*)d_in[5];
    const float* b2    = (const float*)d_in[6];
    const float* gamma = (const float*)d_in[7];
    const float* beta  = (const float*)d_in[8];
    const float* eps   = (const float*)d_in[9];
    const float* linW  = (const float*)d_in[10];
    const float* linb  = (const float*)d_in[11];
    float* out = (float*)d_out;

    char* ws = (char*)d_ws;
    size_t off = 0;
    auto alloc = [&](size_t bytes) -> char* {
        char* p = ws + off;
        off = (off + bytes + 15) & ~(size_t)15;
        return p;
    };
    float* agg    = (float*)alloc((size_t)kN * kH * 4);  // also holds h2 after GEMM2
    float* hcur   = (float*)alloc((size_t)kN * kH * 4);
    float* hmid   = (float*)alloc((size_t)kN * kH * 4);  // also final tanh output y
    int*   rowptr = (int*)alloc((size_t)(kN + 1) * 4);
    int*   cursor = (int*)alloc((size_t)kN * 4);         // deg, then cursor
    int*   colidx = (int*)alloc((size_t)kE * 4);
    float* stats  = (float*)alloc((size_t)kL * 256 * 4); // per layer: [sums 128][sumsq 128]
    int*   gcnt   = (int*)alloc((size_t)kG * 4);
    int*   gp     = (int*)alloc((size_t)(kG + 1) * 4);

    const int* srcp = ei;       // edge_index[0] (source)
    const int* dstp = ei + kE;  // edge_index[1] (target)

    hipMemsetAsync(cursor, 0, (size_t)kN * 4, stream);
    hipMemsetAsync(stats, 0, (size_t)kL * 256 * 4, stream);
    hipMemsetAsync(gcnt, 0, (size_t)kG * 4, stream);

    hist_kernel<<<(kE + 255) / 256, 256, 0, stream>>>(dstp, cursor);
    scan_kernel<<<1, 1024, 0, stream>>>(cursor, rowptr);
    scatter_kernel<<<(kE + 255) / 256, 256, 0, stream>>>(srcp, dstp, cursor, colidx);
    count_kernel<<<(kN + 255) / 256, 256, 0, stream>>>(batch, gcnt);
    gprefix_kernel<<<1, 64, 0, stream>>>(gcnt, gp);

    const int gemm_grid = (kN + 63) / 64;
    for (int l = 0; l < kL; ++l) {
        const float* hin = (l == 0) ? x : hcur;
        gather_kernel<<<(kN + 3) / 4, 256, 0, stream>>>(hin, rowptr, colidx, agg);
        gemm_kernel<0><<<gemm_grid, 256, 0, stream>>>(
            hin, agg, W1 + (size_t)l * kH * kH, b1 + (size_t)l * kH, eps, l, hmid);
        gemm_kernel<1><<<gemm_grid, 256, 0, stream>>>(
            hmid, nullptr, W2 + (size_t)l * kH * kH, b2 + (size_t)l * kH, nullptr, 0, agg);
        stats_kernel<<<512, 256, 0, stream>>>(agg, stats + l * 256, stats + l * 256 + 128);
        bn_kernel<<<2048, 256, 0, stream>>>(agg, hcur, gamma + (size_t)l * kH,
                                            beta + (size_t)l * kH, stats + l * 256,
                                            stats + l * 256 + 128, l == 0 ? 1 : 0);
    }
    gemm_kernel<2><<<gemm_grid, 256, 0, stream>>>(hcur, nullptr, linW, linb, nullptr, 0, hmid);
    pool_kernel<<<kG, 512, 0, stream>>>(hmid, gp, out);
}

// Round 3
// 1091.776 us; speedup vs baseline: 1.5196x; 1.3005x over previous
//
#include <hip/hip_runtime.h>
#include <cstddef>

// GIN forward on MI355X — round 3:
//  (a) batch is sorted -> segment boundaries via neighbor-compare (kills 164us atomic count_kernel)
//  (b) GEMMs -> MFMA bf16 split-precision (hi+lo, 3 terms ~ fp32 accuracy), weights pre-packed
//      once per call into fragment-linear order; A-fragments loaded straight from global.
//      Zero LDS / zero barriers in the GEMM.

namespace {
constexpr int kN = 50000;
constexpr int kE = 800000;
constexpr int kH = 128;
constexpr int kL = 5;
constexpr int kG = 64;
constexpr float kBnEps = 1e-5f;
}

typedef __attribute__((ext_vector_type(8))) short short8v;
typedef __attribute__((ext_vector_type(4))) float f32x4;

__device__ inline unsigned short f2bf(float f) {
    unsigned int u = __float_as_uint(f);
    unsigned int r = (u + 0x7fffu + ((u >> 16) & 1u)) >> 16;  // round-to-nearest-even
    return (unsigned short)r;
}
__device__ inline float bf2f(unsigned short h) {
    return __uint_as_float(((unsigned int)h) << 16);
}

// ---------------- graph build (once per call) ----------------

__global__ void hist_kernel(const int* __restrict__ dst, int* __restrict__ deg) {
    int i = blockIdx.x * blockDim.x + threadIdx.x;
    if (i < kE) atomicAdd(&deg[dst[i]], 1);
}

// single-block exclusive scan over deg[kN]; writes rowptr[kN+1] and resets deg -> cursor
__global__ void scan_kernel(int* __restrict__ deg, int* __restrict__ rowptr) {
    __shared__ int lds[1024];
    const int tid = threadIdx.x;
    const int chunk = (kN + 1023) >> 10;  // 49
    int start = tid * chunk; if (start > kN) start = kN;
    int end = start + chunk; if (end > kN) end = kN;
    int s = 0;
    for (int i = start; i < end; ++i) s += deg[i];
    lds[tid] = s;
    __syncthreads();
    for (int d = 1; d < 1024; d <<= 1) {
        int v = lds[tid];
        if (tid >= d) v += lds[tid - d];
        __syncthreads();
        lds[tid] = v;
        __syncthreads();
    }
    int off = (tid == 0) ? 0 : lds[tid - 1];
    for (int i = start; i < end; ++i) {
        int dv = deg[i];
        rowptr[i] = off;
        deg[i] = off;  // cursor init for scatter
        off += dv;
    }
    if (tid == 1023) rowptr[kN] = off;  // == kE
}

__global__ void scatter_kernel(const int* __restrict__ src, const int* __restrict__ dst,
                               int* __restrict__ cursor, int* __restrict__ col) {
    int i = blockIdx.x * blockDim.x + threadIdx.x;
    if (i < kE) {
        int p = atomicAdd(&cursor[dst[i]], 1);
        col[p] = src[i];
    }
}

// batch is sorted: gp[g] = first row index of graph g, gp[kG] = kN. No atomics.
__global__ void gp_kernel(const int* __restrict__ batch, int* __restrict__ gp) {
    int i = blockIdx.x * blockDim.x + threadIdx.x;
    if (i >= kN) return;
    int b = batch[i];
    if (i == 0) {
        for (int g = 0; g <= b; ++g) gp[g] = 0;
    } else {
        int p = batch[i - 1];
        for (int g = p; g < b; ++g) gp[g + 1] = i;
    }
    if (i == kN - 1) {
        for (int g = b; g < kG; ++g) gp[g + 1] = kN;
    }
}

// ---------------- weight pre-pack: 11 matrices -> MFMA fragment order, hi/lo bf16 ----------
// frag f = (kc*8 + t)*64 + lane ; element e: src W[kc*32 + (lane>>4)*8 + e][t*16 + (lane&15)]
// layout per matrix: [16384 shorts hi][16384 shorts lo]
__global__ __launch_bounds__(256) void pack_kernel(const float* __restrict__ W1,
                                                   const float* __restrict__ W2,
                                                   const float* __restrict__ linW,
                                                   short* __restrict__ wpk) {
    const int m = blockIdx.x;  // 0..10
    const float* src = (m < 5) ? W1 + (size_t)m * 16384
                               : (m < 10 ? W2 + (size_t)(m - 5) * 16384 : linW);
    for (int f = threadIdx.x; f < 2048; f += 256) {
        int kc = f >> 9;
        int t = (f >> 6) & 7;
        int l = f & 63;
        int kr = kc * 32 + ((l >> 4) << 3);
        int cl = t * 16 + (l & 15);
        short8v hi, lo;
#pragma unroll
        for (int e = 0; e < 8; ++e) {
            float v = src[(size_t)(kr + e) * kH + cl];
            unsigned short h = f2bf(v);
            hi[e] = (short)h;
            lo[e] = (short)f2bf(v - bf2f(h));
        }
        *reinterpret_cast<short8v*>(wpk + (size_t)m * 32768 + (size_t)f * 8) = hi;
        *reinterpret_cast<short8v*>(wpk + (size_t)m * 32768 + 16384 + (size_t)f * 8) = lo;
    }
}

// ---------------- aggregation: agg[n] = sum_{j in N(n)} h[col[j]] ----------------
__global__ __launch_bounds__(256) void gather_kernel(const float* __restrict__ h,
                                                     const int* __restrict__ rowptr,
                                                     const int* __restrict__ col,
                                                     float* __restrict__ agg) {
    const int lane = threadIdx.x & 63;
    const int n = blockIdx.x * 4 + (threadIdx.x >> 6);
    if (n >= kN) return;
    const int e0 = rowptr[n], e1 = rowptr[n + 1];
    float ax = 0.f, ay = 0.f;
    const float2* hp = reinterpret_cast<const float2*>(h);
    for (int e = e0; e < e1; ++e) {
        int s = col[e];
        float2 v = hp[(size_t)s * 64 + lane];
        ax += v.x;
        ay += v.y;
    }
    reinterpret_cast<float2*>(agg)[(size_t)n * 64 + lane] = make_float2(ax, ay);
}

// ---------------- MFMA GEMM: one wave per 16-row tile, full 128 cols -------------
// MODE 0: A = (1+eps)*A0 + A1, relu->out
// MODE 1: A = A0,              relu->out
// MODE 2: A = A0,              tanh->out
template <int MODE>
__global__ __launch_bounds__(256) void mfma_gemm(const float* __restrict__ A0,
                                                 const float* __restrict__ A1,
                                                 const short* __restrict__ wpk, int mat,
                                                 const float* __restrict__ bias,
                                                 const float* __restrict__ eps_p, int layer,
                                                 float* __restrict__ out) {
    const int lane = threadIdx.x & 63;
    const int tile = blockIdx.x * 4 + (threadIdx.x >> 6);
    if (tile * 16 >= kN) return;  // kN % 16 == 0, so valid tiles are full
    const int row0 = tile * 16;
    const int m15 = lane & 15;
    const int kg = lane >> 4;  // 0..3
    const int arow = row0 + m15;

    float scale = 1.0f;
    if (MODE == 0) scale = 1.0f + eps_p[layer];

    const short8v* wp = reinterpret_cast<const short8v*>(wpk + (size_t)mat * 32768);
    // wp[f] = hi frag, wp[2048 + f] = lo frag

    f32x4 acc[8];
#pragma unroll
    for (int t = 0; t < 8; ++t) acc[t] = (f32x4)0.0f;

#pragma unroll
    for (int kc = 0; kc < 4; ++kc) {
        const float4* ap =
            reinterpret_cast<const float4*>(A0 + (size_t)arow * kH + kc * 32 + kg * 8);
        float4 v0 = ap[0], v1 = ap[1];
        float a[8] = {v0.x, v0.y, v0.z, v0.w, v1.x, v1.y, v1.z, v1.w};
        if (MODE == 0) {
            const float4* bp =
                reinterpret_cast<const float4*>(A1 + (size_t)arow * kH + kc * 32 + kg * 8);
            float4 u0 = bp[0], u1 = bp[1];
            float u[8] = {u0.x, u0.y, u0.z, u0.w, u1.x, u1.y, u1.z, u1.w};
#pragma unroll
            for (int e = 0; e < 8; ++e) a[e] = scale * a[e] + u[e];
        }
        short8v ah, al;
#pragma unroll
        for (int e = 0; e < 8; ++e) {
            unsigned short h = f2bf(a[e]);
            ah[e] = (short)h;
            al[e] = (short)f2bf(a[e] - bf2f(h));
        }
#pragma unroll
        for (int t = 0; t < 8; ++t) {
            int f = (kc * 8 + t) * 64 + lane;
            short8v wh = wp[f];
            short8v wl = wp[2048 + f];
            acc[t] = __builtin_amdgcn_mfma_f32_16x16x32_bf16(al, wh, acc[t], 0, 0, 0);
            acc[t] = __builtin_amdgcn_mfma_f32_16x16x32_bf16(ah, wl, acc[t], 0, 0, 0);
            acc[t] = __builtin_amdgcn_mfma_f32_16x16x32_bf16(ah, wh, acc[t], 0, 0, 0);
        }
    }

    // D layout: row = (lane>>4)*4 + r, col = lane&15 (within 16x16 tile t)
    const int orow0 = row0 + kg * 4;
#pragma unroll
    for (int t = 0; t < 8; ++t) {
        int cl = t * 16 + m15;
        float b = bias[cl];
#pragma unroll
        for (int r = 0; r < 4; ++r) {
            float o = acc[t][r] + b;
            if (MODE < 2)
                o = fmaxf(o, 0.f);
            else
                o = tanhf(o);
            out[(size_t)(orow0 + r) * kH + cl] = o;
        }
    }
}

// ---------------- segment mean pool ----------------
__global__ __launch_bounds__(512) void pool_kernel(const float* __restrict__ y,
                                                   const int* __restrict__ gp,
                                                   float* __restrict__ out) {
    __shared__ float part[4][kH];
    const int g = blockIdx.x;
    const int c = threadIdx.x & 127;
    const int q = threadIdx.x >> 7;  // 0..3
    const int s = gp[g], e = gp[g + 1];
    float acc = 0.f;
    for (int r = s + q; r < e; r += 4) acc += y[(size_t)r * kH + c];
    part[q][c] = acc;
    __syncthreads();
    if (q == 0) {
        float v = part[0][c] + part[1][c] + part[2][c] + part[3][c];
        out[g * kH + c] = v / fmaxf((float)(e - s), 1.0f);
    }
}

// ---------------- per-column sums / sums-of-squares ----------------
__global__ __launch_bounds__(256) void stats_kernel(const float* __restrict__ h,
                                                    float* __restrict__ sums,
                                                    float* __restrict__ sumsq) {
    __shared__ float ls[2][kH], lq[2][kH];
    const int tid = threadIdx.x;
    const int c = tid & 127;
    const int y = tid >> 7;
    float s = 0.f, q = 0.f;
    for (int r = blockIdx.x * 2 + y; r < kN; r += gridDim.x * 2) {
        float v = h[(size_t)r * kH + c];
        s += v;
        q += v * v;
    }
    ls[y][c] = s;
    lq[y][c] = q;
    __syncthreads();
    if (y == 0) {
        atomicAdd(&sums[c], ls[0][c] + ls[1][c]);
        atomicAdd(&sumsq[c], lq[0][c] + lq[1][c]);
    }
}

// ---------------- BN (+ optional relu + residual) ----------------
__global__ __launch_bounds__(256) void bn_kernel(const float* __restrict__ h2,
                                                 float* __restrict__ hcur,
                                                 const float* __restrict__ gamma,
                                                 const float* __restrict__ beta,
                                                 const float* __restrict__ sums,
                                                 const float* __restrict__ sumsq,
                                                 int first) {
    const float invN = 1.0f / (float)kN;
    const size_t total = (size_t)kN * (kH / 4);
    const size_t stride = (size_t)gridDim.x * blockDim.x;
    for (size_t i = (size_t)blockIdx.x * blockDim.x + threadIdx.x; i < total; i += stride) {
        int c0 = ((int)(i & 31)) * 4;
        float4 s4 = *reinterpret_cast<const float4*>(sums + c0);
        float4 q4 = *reinterpret_cast<const float4*>(sumsq + c0);
        float4 g4 = *reinterpret_cast<const float4*>(gamma + c0);
        float4 be4 = *reinterpret_cast<const float4*>(beta + c0);
        float4 h4 = reinterpret_cast<const float4*>(h2)[i];
        float o0, o1, o2, o3;
        {
            float mu = s4.x * invN, var = fmaxf(q4.x * invN - mu * mu, 0.f);
            o0 = (h4.x - mu) * rsqrtf(var + kBnEps) * g4.x + be4.x;
        }
        {
            float mu = s4.y * invN, var = fmaxf(q4.y * invN - mu * mu, 0.f);
            o1 = (h4.y - mu) * rsqrtf(var + kBnEps) * g4.y + be4.y;
        }
        {
            float mu = s4.z * invN, var = fmaxf(q4.z * invN - mu * mu, 0.f);
            o2 = (h4.z - mu) * rsqrtf(var + kBnEps) * g4.z + be4.z;
        }
        {
            float mu = s4.w * invN, var = fmaxf(q4.w * invN - mu * mu, 0.f);
            o3 = (h4.w - mu) * rsqrtf(var + kBnEps) * g4.w + be4.w;
        }
        if (first) {
            reinterpret_cast<float4*>(hcur)[i] = make_float4(o0, o1, o2, o3);
        } else {
            float4 p = reinterpret_cast<float4*>(hcur)[i];
            p.x += fmaxf(o0, 0.f);
            p.y += fmaxf(o1, 0.f);
            p.z += fmaxf(o2, 0.f);
            p.w += fmaxf(o3, 0.f);
            reinterpret_cast<float4*>(hcur)[i] = p;
        }
    }
}

// ---------------- launch ----------------
extern "C" void kernel_launch(void* const* d_in, const int* in_sizes, int n_in,
                              void* d_out, int out_size, void* d_ws, size_t ws_size,
                              hipStream_t stream) {
    const float* x     = (const float*)d_in[0];
    const int*   ei    = (const int*)d_in[1];
    const int*   batch = (const int*)d_in[2];
    const float* W1    = (const float*)d_in[3];
    const float* b1    = (const float*)d_in[4];
    const float* W2    = (const float*)d_in[5];
    const float* b2    = (const float*)d_in[6];
    const float* gamma = (const float*)d_in[7];
    const float* beta  = (const float*)d_in[8];
    const float* eps   = (const float*)d_in[9];
    const float* linW  = (const float*)d_in[10];
    const float* linb  = (const float*)d_in[11];
    float* out = (float*)d_out;

    char* ws = (char*)d_ws;
    size_t off = 0;
    auto alloc = [&](size_t bytes) -> char* {
        char* p = ws + off;
        off = (off + bytes + 15) & ~(size_t)15;
        return p;
    };
    float* agg    = (float*)alloc((size_t)kN * kH * 4);  // also holds h2 after GEMM2
    float* hcur   = (float*)alloc((size_t)kN * kH * 4);
    float* hmid   = (float*)alloc((size_t)kN * kH * 4);  // also final tanh output y
    int*   rowptr = (int*)alloc((size_t)(kN + 1) * 4);
    int*   cursor = (int*)alloc((size_t)kN * 4);         // deg, then cursor
    int*   colidx = (int*)alloc((size_t)kE * 4);
    float* stats  = (float*)alloc((size_t)kL * 256 * 4); // per layer: [sums 128][sumsq 128]
    int*   gp     = (int*)alloc((size_t)(kG + 1) * 4);
    short* wpk    = (short*)alloc((size_t)11 * 32768 * 2);  // 11 matrices, hi+lo planes

    const int* srcp = ei;       // edge_index[0] (source)
    const int* dstp = ei + kE;  // edge_index[1] (target)

    hipMemsetAsync(cursor, 0, (size_t)kN * 4, stream);
    hipMemsetAsync(stats, 0, (size_t)kL * 256 * 4, stream);

    hist_kernel<<<(kE + 255) / 256, 256, 0, stream>>>(dstp, cursor);
    scan_kernel<<<1, 1024, 0, stream>>>(cursor, rowptr);
    scatter_kernel<<<(kE + 255) / 256, 256, 0, stream>>>(srcp, dstp, cursor, colidx);
    gp_kernel<<<(kN + 255) / 256, 256, 0, stream>>>(batch, gp);
    pack_kernel<<<11, 256, 0, stream>>>(W1, W2, linW, wpk);

    const int gemm_grid = (kN / 16 + 3) / 4;  // 3125 tiles -> 782 blocks
    for (int l = 0; l < kL; ++l) {
        const float* hin = (l == 0) ? x : hcur;
        gather_kernel<<<(kN + 3) / 4, 256, 0, stream>>>(hin, rowptr, colidx, agg);
        mfma_gemm<0><<<gemm_grid, 256, 0, stream>>>(hin, agg, wpk, l, b1 + (size_t)l * kH,
                                                    eps, l, hmid);
        mfma_gemm<1><<<gemm_grid, 256, 0, stream>>>(hmid, nullptr, wpk, 5 + l,
                                                    b2 + (size_t)l * kH, nullptr, 0, agg);
        stats_kernel<<<512, 256, 0, stream>>>(agg, stats + l * 256, stats + l * 256 + 128);
        bn_kernel<<<2048, 256, 0, stream>>>(agg, hcur, gamma + (size_t)l * kH,
                                            beta + (size_t)l * kH, stats + l * 256,
                                            stats + l * 256 + 128, l == 0 ? 1 : 0);
    }
    mfma_gemm<2><<<gemm_grid, 256, 0, stream>>>(hcur, nullptr, wpk, 10, linb, nullptr, 0, hmid);
    pool_kernel<<<kG, 512, 0, stream>>>(hmid, gp, out);
}

// Round 4
// 1004.560 us; speedup vs baseline: 1.6515x; 1.0868x over previous
//
#include <hip/hip_runtime.h>
#include <cstddef>

// GIN forward on MI355X — round 4: multiblock CSR scan (kills 109us single-block scan_kernel).
// R3 baseline: MFMA split-bf16 GEMMs + no-atomic segment pooling. absmax 2e-3.

namespace {
constexpr int kN = 50000;
constexpr int kE = 800000;
constexpr int kH = 128;
constexpr int kL = 5;
constexpr int kG = 64;
constexpr float kBnEps = 1e-5f;
constexpr int kScanB = 512;
constexpr int kScanG = (kN + kScanB - 1) / kScanB;  // 98
}

typedef __attribute__((ext_vector_type(8))) short short8v;
typedef __attribute__((ext_vector_type(4))) float f32x4;

__device__ inline unsigned short f2bf(float f) {
    unsigned int u = __float_as_uint(f);
    unsigned int r = (u + 0x7fffu + ((u >> 16) & 1u)) >> 16;  // round-to-nearest-even
    return (unsigned short)r;
}
__device__ inline float bf2f(unsigned short h) {
    return __uint_as_float(((unsigned int)h) << 16);
}

// ---------------- graph build (once per call) ----------------

__global__ void hist_kernel(const int* __restrict__ dst, int* __restrict__ deg) {
    int i = blockIdx.x * blockDim.x + threadIdx.x;
    if (i < kE) atomicAdd(&deg[dst[i]], 1);
}

// phase 1: per-block exclusive scan of deg -> local, block totals -> bsum
__global__ __launch_bounds__(kScanB) void scan1_kernel(const int* __restrict__ deg,
                                                       int* __restrict__ local,
                                                       int* __restrict__ bsum) {
    const int i = blockIdx.x * kScanB + threadIdx.x;
    const int lane = threadIdx.x & 63;
    const int wid = threadIdx.x >> 6;  // 0..7
    int v = (i < kN) ? deg[i] : 0;
    int s = v;
#pragma unroll
    for (int d = 1; d < 64; d <<= 1) {
        int t = __shfl_up(s, d);
        if (lane >= d) s += t;
    }
    __shared__ int wsum[8];
    if (lane == 63) wsum[wid] = s;
    __syncthreads();
    if (threadIdx.x < 8) {
        int w = wsum[threadIdx.x];
#pragma unroll
        for (int d = 1; d < 8; d <<= 1) {
            int t = __shfl_up(w, d);
            if (lane >= d) w += t;
        }
        wsum[threadIdx.x] = w;
    }
    __syncthreads();
    int woff = (wid == 0) ? 0 : wsum[wid - 1];
    int incl = s + woff;
    if (i < kN) local[i] = incl - v;  // exclusive prefix within block
    if (threadIdx.x == kScanB - 1) bsum[blockIdx.x] = incl;  // block total
}

// phase 2: exclusive scan over kScanG block totals (one block, 128 thr)
__global__ void scan2_kernel(int* __restrict__ bsum) {
    const int t = threadIdx.x;
    const int lane = t & 63;
    const int wid = t >> 6;  // 0..1
    int v = (t < kScanG) ? bsum[t] : 0;
    int s = v;
#pragma unroll
    for (int d = 1; d < 64; d <<= 1) {
        int u = __shfl_up(s, d);
        if (lane >= d) s += u;
    }
    __shared__ int ws[2];
    if (lane == 63) ws[wid] = s;
    __syncthreads();
    int incl = s + ((wid == 1) ? ws[0] : 0);
    if (t < kScanG) bsum[t] = incl - v;  // exclusive block offsets
}

// phase 3: rowptr/cursor = local + block offset
__global__ __launch_bounds__(kScanB) void scan3_kernel(const int* __restrict__ local,
                                                       const int* __restrict__ bsum,
                                                       int* __restrict__ rowptr,
                                                       int* __restrict__ cursor) {
    const int i = blockIdx.x * kScanB + threadIdx.x;
    if (i < kN) {
        int v = local[i] + bsum[blockIdx.x];
        rowptr[i] = v;
        cursor[i] = v;
    }
    if (i == 0) rowptr[kN] = kE;
}

__global__ void scatter_kernel(const int* __restrict__ src, const int* __restrict__ dst,
                               int* __restrict__ cursor, int* __restrict__ col) {
    int i = blockIdx.x * blockDim.x + threadIdx.x;
    if (i < kE) {
        int p = atomicAdd(&cursor[dst[i]], 1);
        col[p] = src[i];
    }
}

// batch is sorted: gp[g] = first row index of graph g, gp[kG] = kN. No atomics.
__global__ void gp_kernel(const int* __restrict__ batch, int* __restrict__ gp) {
    int i = blockIdx.x * blockDim.x + threadIdx.x;
    if (i >= kN) return;
    int b = batch[i];
    if (i == 0) {
        for (int g = 0; g <= b; ++g) gp[g] = 0;
    } else {
        int p = batch[i - 1];
        for (int g = p; g < b; ++g) gp[g + 1] = i;
    }
    if (i == kN - 1) {
        for (int g = b; g < kG; ++g) gp[g + 1] = kN;
    }
}

// ---------------- weight pre-pack: 11 matrices -> MFMA fragment order, hi/lo bf16 ----------
__global__ __launch_bounds__(256) void pack_kernel(const float* __restrict__ W1,
                                                   const float* __restrict__ W2,
                                                   const float* __restrict__ linW,
                                                   short* __restrict__ wpk) {
    const int m = blockIdx.x;  // 0..10
    const float* src = (m < 5) ? W1 + (size_t)m * 16384
                               : (m < 10 ? W2 + (size_t)(m - 5) * 16384 : linW);
    for (int f = threadIdx.x; f < 2048; f += 256) {
        int kc = f >> 9;
        int t = (f >> 6) & 7;
        int l = f & 63;
        int kr = kc * 32 + ((l >> 4) << 3);
        int cl = t * 16 + (l & 15);
        short8v hi, lo;
#pragma unroll
        for (int e = 0; e < 8; ++e) {
            float v = src[(size_t)(kr + e) * kH + cl];
            unsigned short h = f2bf(v);
            hi[e] = (short)h;
            lo[e] = (short)f2bf(v - bf2f(h));
        }
        *reinterpret_cast<short8v*>(wpk + (size_t)m * 32768 + (size_t)f * 8) = hi;
        *reinterpret_cast<short8v*>(wpk + (size_t)m * 32768 + 16384 + (size_t)f * 8) = lo;
    }
}

// ---------------- aggregation: agg[n] = sum_{j in N(n)} h[col[j]] ----------------
__global__ __launch_bounds__(256) void gather_kernel(const float* __restrict__ h,
                                                     const int* __restrict__ rowptr,
                                                     const int* __restrict__ col,
                                                     float* __restrict__ agg) {
    const int lane = threadIdx.x & 63;
    const int n = blockIdx.x * 4 + (threadIdx.x >> 6);
    if (n >= kN) return;
    const int e0 = rowptr[n], e1 = rowptr[n + 1];
    float ax = 0.f, ay = 0.f;
    const float2* hp = reinterpret_cast<const float2*>(h);
    for (int e = e0; e < e1; ++e) {
        int s = col[e];
        float2 v = hp[(size_t)s * 64 + lane];
        ax += v.x;
        ay += v.y;
    }
    reinterpret_cast<float2*>(agg)[(size_t)n * 64 + lane] = make_float2(ax, ay);
}

// ---------------- MFMA GEMM: one wave per 16-row tile, full 128 cols -------------
// MODE 0: A = (1+eps)*A0 + A1, relu->out
// MODE 1: A = A0,              relu->out
// MODE 2: A = A0,              tanh->out
template <int MODE>
__global__ __launch_bounds__(256) void mfma_gemm(const float* __restrict__ A0,
                                                 const float* __restrict__ A1,
                                                 const short* __restrict__ wpk, int mat,
                                                 const float* __restrict__ bias,
                                                 const float* __restrict__ eps_p, int layer,
                                                 float* __restrict__ out) {
    const int lane = threadIdx.x & 63;
    const int tile = blockIdx.x * 4 + (threadIdx.x >> 6);
    if (tile * 16 >= kN) return;
    const int row0 = tile * 16;
    const int m15 = lane & 15;
    const int kg = lane >> 4;  // 0..3
    const int arow = row0 + m15;

    float scale = 1.0f;
    if (MODE == 0) scale = 1.0f + eps_p[layer];

    const short8v* wp = reinterpret_cast<const short8v*>(wpk + (size_t)mat * 32768);

    f32x4 acc[8];
#pragma unroll
    for (int t = 0; t < 8; ++t) acc[t] = (f32x4)0.0f;

#pragma unroll
    for (int kc = 0; kc < 4; ++kc) {
        const float4* ap =
            reinterpret_cast<const float4*>(A0 + (size_t)arow * kH + kc * 32 + kg * 8);
        float4 v0 = ap[0], v1 = ap[1];
        float a[8] = {v0.x, v0.y, v0.z, v0.w, v1.x, v1.y, v1.z, v1.w};
        if (MODE == 0) {
            const float4* bp =
                reinterpret_cast<const float4*>(A1 + (size_t)arow * kH + kc * 32 + kg * 8);
            float4 u0 = bp[0], u1 = bp[1];
            float u[8] = {u0.x, u0.y, u0.z, u0.w, u1.x, u1.y, u1.z, u1.w};
#pragma unroll
            for (int e = 0; e < 8; ++e) a[e] = scale * a[e] + u[e];
        }
        short8v ah, al;
#pragma unroll
        for (int e = 0; e < 8; ++e) {
            unsigned short h = f2bf(a[e]);
            ah[e] = (short)h;
            al[e] = (short)f2bf(a[e] - bf2f(h));
        }
#pragma unroll
        for (int t = 0; t < 8; ++t) {
            int f = (kc * 8 + t) * 64 + lane;
            short8v wh = wp[f];
            short8v wl = wp[2048 + f];
            acc[t] = __builtin_amdgcn_mfma_f32_16x16x32_bf16(al, wh, acc[t], 0, 0, 0);
            acc[t] = __builtin_amdgcn_mfma_f32_16x16x32_bf16(ah, wl, acc[t], 0, 0, 0);
            acc[t] = __builtin_amdgcn_mfma_f32_16x16x32_bf16(ah, wh, acc[t], 0, 0, 0);
        }
    }

    const int orow0 = row0 + kg * 4;
#pragma unroll
    for (int t = 0; t < 8; ++t) {
        int cl = t * 16 + m15;
        float b = bias[cl];
#pragma unroll
        for (int r = 0; r < 4; ++r) {
            float o = acc[t][r] + b;
            if (MODE < 2)
                o = fmaxf(o, 0.f);
            else
                o = tanhf(o);
            out[(size_t)(orow0 + r) * kH + cl] = o;
        }
    }
}

// ---------------- segment mean pool ----------------
__global__ __launch_bounds__(512) void pool_kernel(const float* __restrict__ y,
                                                   const int* __restrict__ gp,
                                                   float* __restrict__ out) {
    __shared__ float part[4][kH];
    const int g = blockIdx.x;
    const int c = threadIdx.x & 127;
    const int q = threadIdx.x >> 7;  // 0..3
    const int s = gp[g], e = gp[g + 1];
    float acc = 0.f;
    for (int r = s + q; r < e; r += 4) acc += y[(size_t)r * kH + c];
    part[q][c] = acc;
    __syncthreads();
    if (q == 0) {
        float v = part[0][c] + part[1][c] + part[2][c] + part[3][c];
        out[g * kH + c] = v / fmaxf((float)(e - s), 1.0f);
    }
}

// ---------------- per-column sums / sums-of-squares ----------------
__global__ __launch_bounds__(256) void stats_kernel(const float* __restrict__ h,
                                                    float* __restrict__ sums,
                                                    float* __restrict__ sumsq) {
    __shared__ float ls[2][kH], lq[2][kH];
    const int tid = threadIdx.x;
    const int c = tid & 127;
    const int y = tid >> 7;
    float s = 0.f, q = 0.f;
    for (int r = blockIdx.x * 2 + y; r < kN; r += gridDim.x * 2) {
        float v = h[(size_t)r * kH + c];
        s += v;
        q += v * v;
    }
    ls[y][c] = s;
    lq[y][c] = q;
    __syncthreads();
    if (y == 0) {
        atomicAdd(&sums[c], ls[0][c] + ls[1][c]);
        atomicAdd(&sumsq[c], lq[0][c] + lq[1][c]);
    }
}

// ---------------- BN (+ optional relu + residual) ----------------
__global__ __launch_bounds__(256) void bn_kernel(const float* __restrict__ h2,
                                                 float* __restrict__ hcur,
                                                 const float* __restrict__ gamma,
                                                 const float* __restrict__ beta,
                                                 const float* __restrict__ sums,
                                                 const float* __restrict__ sumsq,
                                                 int first) {
    const float invN = 1.0f / (float)kN;
    const size_t total = (size_t)kN * (kH / 4);
    const size_t stride = (size_t)gridDim.x * blockDim.x;
    for (size_t i = (size_t)blockIdx.x * blockDim.x + threadIdx.x; i < total; i += stride) {
        int c0 = ((int)(i & 31)) * 4;
        float4 s4 = *reinterpret_cast<const float4*>(sums + c0);
        float4 q4 = *reinterpret_cast<const float4*>(sumsq + c0);
        float4 g4 = *reinterpret_cast<const float4*>(gamma + c0);
        float4 be4 = *reinterpret_cast<const float4*>(beta + c0);
        float4 h4 = reinterpret_cast<const float4*>(h2)[i];
        float o0, o1, o2, o3;
        {
            float mu = s4.x * invN, var = fmaxf(q4.x * invN - mu * mu, 0.f);
            o0 = (h4.x - mu) * rsqrtf(var + kBnEps) * g4.x + be4.x;
        }
        {
            float mu = s4.y * invN, var = fmaxf(q4.y * invN - mu * mu, 0.f);
            o1 = (h4.y - mu) * rsqrtf(var + kBnEps) * g4.y + be4.y;
        }
        {
            float mu = s4.z * invN, var = fmaxf(q4.z * invN - mu * mu, 0.f);
            o2 = (h4.z - mu) * rsqrtf(var + kBnEps) * g4.z + be4.z;
        }
        {
            float mu = s4.w * invN, var = fmaxf(q4.w * invN - mu * mu, 0.f);
            o3 = (h4.w - mu) * rsqrtf(var + kBnEps) * g4.w + be4.w;
        }
        if (first) {
            reinterpret_cast<float4*>(hcur)[i] = make_float4(o0, o1, o2, o3);
        } else {
            float4 p = reinterpret_cast<float4*>(hcur)[i];
            p.x += fmaxf(o0, 0.f);
            p.y += fmaxf(o1, 0.f);
            p.z += fmaxf(o2, 0.f);
            p.w += fmaxf(o3, 0.f);
            reinterpret_cast<float4*>(hcur)[i] = p;
        }
    }
}

// ---------------- launch ----------------
extern "C" void kernel_launch(void* const* d_in, const int* in_sizes, int n_in,
                              void* d_out, int out_size, void* d_ws, size_t ws_size,
                              hipStream_t stream) {
    const float* x     = (const float*)d_in[0];
    const int*   ei    = (const int*)d_in[1];
    const int*   batch = (const int*)d_in[2];
    const float* W1    = (const float*)d_in[3];
    const float* b1    = (const float*)d_in[4];
    const float* W2    = (const float*)d_in[5];
    const float* b2    = (const float*)d_in[6];
    const float* gamma = (const float*)d_in[7];
    const float* beta  = (const float*)d_in[8];
    const float* eps   = (const float*)d_in[9];
    const float* linW  = (const float*)d_in[10];
    const float* linb  = (const float*)d_in[11];
    float* out = (float*)d_out;

    char* ws = (char*)d_ws;
    size_t off = 0;
    auto alloc = [&](size_t bytes) -> char* {
        char* p = ws + off;
        off = (off + bytes + 15) & ~(size_t)15;
        return p;
    };
    float* agg    = (float*)alloc((size_t)kN * kH * 4);  // also holds h2 after GEMM2
    float* hcur   = (float*)alloc((size_t)kN * kH * 4);
    float* hmid   = (float*)alloc((size_t)kN * kH * 4);  // also final tanh output y
    int*   rowptr = (int*)alloc((size_t)(kN + 1) * 4);
    int*   deg    = (int*)alloc((size_t)kN * 4);
    int*   local  = (int*)alloc((size_t)kN * 4);
    int*   cursor = (int*)alloc((size_t)kN * 4);
    int*   bsum   = (int*)alloc((size_t)128 * 4);
    int*   colidx = (int*)alloc((size_t)kE * 4);
    float* stats  = (float*)alloc((size_t)kL * 256 * 4); // per layer: [sums 128][sumsq 128]
    int*   gp     = (int*)alloc((size_t)(kG + 1) * 4);
    short* wpk    = (short*)alloc((size_t)11 * 32768 * 2);  // 11 matrices, hi+lo planes

    const int* srcp = ei;       // edge_index[0] (source)
    const int* dstp = ei + kE;  // edge_index[1] (target)

    hipMemsetAsync(deg, 0, (size_t)kN * 4, stream);
    hipMemsetAsync(stats, 0, (size_t)kL * 256 * 4, stream);

    hist_kernel<<<(kE + 255) / 256, 256, 0, stream>>>(dstp, deg);
    scan1_kernel<<<kScanG, kScanB, 0, stream>>>(deg, local, bsum);
    scan2_kernel<<<1, 128, 0, stream>>>(bsum);
    scan3_kernel<<<kScanG, kScanB, 0, stream>>>(local, bsum, rowptr, cursor);
    scatter_kernel<<<(kE + 255) / 256, 256, 0, stream>>>(srcp, dstp, cursor, colidx);
    gp_kernel<<<(kN + 255) / 256, 256, 0, stream>>>(batch, gp);
    pack_kernel<<<11, 256, 0, stream>>>(W1, W2, linW, wpk);

    const int gemm_grid = (kN / 16 + 3) / 4;  // 3125 tiles -> 782 blocks
    for (int l = 0; l < kL; ++l) {
        const float* hin = (l == 0) ? x : hcur;
        gather_kernel<<<(kN + 3) / 4, 256, 0, stream>>>(hin, rowptr, colidx, agg);
        mfma_gemm<0><<<gemm_grid, 256, 0, stream>>>(hin, agg, wpk, l, b1 + (size_t)l * kH,
                                                    eps, l, hmid);
        mfma_gemm<1><<<gemm_grid, 256, 0, stream>>>(hmid, nullptr, wpk, 5 + l,
                                                    b2 + (size_t)l * kH, nullptr, 0, agg);
        stats_kernel<<<512, 256, 0, stream>>>(agg, stats + l * 256, stats + l * 256 + 128);
        bn_kernel<<<2048, 256, 0, stream>>>(agg, hcur, gamma + (size_t)l * kH,
                                            beta + (size_t)l * kH, stats + l * 256,
                                            stats + l * 256 + 128, l == 0 ? 1 : 0);
    }
    mfma_gemm<2><<<gemm_grid, 256, 0, stream>>>(hcur, nullptr, wpk, 10, linb, nullptr, 0, hmid);
    pool_kernel<<<kG, 512, 0, stream>>>(hmid, gp, out);
}

// Round 5
// 845.281 us; speedup vs baseline: 1.9627x; 1.1884x over previous
//
#include <hip/hip_runtime.h>
#include <cstddef>

// GIN forward on MI355X — round 5: latency-hiding gather (8-wide edge unroll, masked rounds,
// scalar-path col loads). R4: gather was 91.6us x5 = 46% of runtime, ~1 outstanding row
// load per wave (dependent col->row chain). This round pipelines 8 row loads per round.

namespace {
constexpr int kN = 50000;
constexpr int kE = 800000;
constexpr int kH = 128;
constexpr int kL = 5;
constexpr int kG = 64;
constexpr float kBnEps = 1e-5f;
constexpr int kScanB = 512;
constexpr int kScanG = (kN + kScanB - 1) / kScanB;  // 98
}

typedef __attribute__((ext_vector_type(8))) short short8v;
typedef __attribute__((ext_vector_type(4))) float f32x4;

__device__ inline unsigned short f2bf(float f) {
    unsigned int u = __float_as_uint(f);
    unsigned int r = (u + 0x7fffu + ((u >> 16) & 1u)) >> 16;  // round-to-nearest-even
    return (unsigned short)r;
}
__device__ inline float bf2f(unsigned short h) {
    return __uint_as_float(((unsigned int)h) << 16);
}

// ---------------- graph build (once per call) ----------------

__global__ void hist_kernel(const int* __restrict__ dst, int* __restrict__ deg) {
    int i = blockIdx.x * blockDim.x + threadIdx.x;
    if (i < kE) atomicAdd(&deg[dst[i]], 1);
}

__global__ __launch_bounds__(kScanB) void scan1_kernel(const int* __restrict__ deg,
                                                       int* __restrict__ local,
                                                       int* __restrict__ bsum) {
    const int i = blockIdx.x * kScanB + threadIdx.x;
    const int lane = threadIdx.x & 63;
    const int wid = threadIdx.x >> 6;  // 0..7
    int v = (i < kN) ? deg[i] : 0;
    int s = v;
#pragma unroll
    for (int d = 1; d < 64; d <<= 1) {
        int t = __shfl_up(s, d);
        if (lane >= d) s += t;
    }
    __shared__ int wsum[8];
    if (lane == 63) wsum[wid] = s;
    __syncthreads();
    if (threadIdx.x < 8) {
        int w = wsum[threadIdx.x];
#pragma unroll
        for (int d = 1; d < 8; d <<= 1) {
            int t = __shfl_up(w, d);
            if (lane >= d) w += t;
        }
        wsum[threadIdx.x] = w;
    }
    __syncthreads();
    int woff = (wid == 0) ? 0 : wsum[wid - 1];
    int incl = s + woff;
    if (i < kN) local[i] = incl - v;
    if (threadIdx.x == kScanB - 1) bsum[blockIdx.x] = incl;
}

__global__ void scan2_kernel(int* __restrict__ bsum) {
    const int t = threadIdx.x;
    const int lane = t & 63;
    const int wid = t >> 6;  // 0..1
    int v = (t < kScanG) ? bsum[t] : 0;
    int s = v;
#pragma unroll
    for (int d = 1; d < 64; d <<= 1) {
        int u = __shfl_up(s, d);
        if (lane >= d) s += u;
    }
    __shared__ int ws[2];
    if (lane == 63) ws[wid] = s;
    __syncthreads();
    int incl = s + ((wid == 1) ? ws[0] : 0);
    if (t < kScanG) bsum[t] = incl - v;
}

__global__ __launch_bounds__(kScanB) void scan3_kernel(const int* __restrict__ local,
                                                       const int* __restrict__ bsum,
                                                       int* __restrict__ rowptr,
                                                       int* __restrict__ cursor) {
    const int i = blockIdx.x * kScanB + threadIdx.x;
    if (i < kN) {
        int v = local[i] + bsum[blockIdx.x];
        rowptr[i] = v;
        cursor[i] = v;
    }
    if (i == 0) rowptr[kN] = kE;
}

__global__ void scatter_kernel(const int* __restrict__ src, const int* __restrict__ dst,
                               int* __restrict__ cursor, int* __restrict__ col) {
    int i = blockIdx.x * blockDim.x + threadIdx.x;
    if (i < kE) {
        int p = atomicAdd(&cursor[dst[i]], 1);
        col[p] = src[i];
    }
}

// batch is sorted: gp[g] = first row index of graph g, gp[kG] = kN. No atomics.
__global__ void gp_kernel(const int* __restrict__ batch, int* __restrict__ gp) {
    int i = blockIdx.x * blockDim.x + threadIdx.x;
    if (i >= kN) return;
    int b = batch[i];
    if (i == 0) {
        for (int g = 0; g <= b; ++g) gp[g] = 0;
    } else {
        int p = batch[i - 1];
        for (int g = p; g < b; ++g) gp[g + 1] = i;
    }
    if (i == kN - 1) {
        for (int g = b; g < kG; ++g) gp[g + 1] = kN;
    }
}

// ---------------- weight pre-pack: 11 matrices -> MFMA fragment order, hi/lo bf16 ----------
__global__ __launch_bounds__(256) void pack_kernel(const float* __restrict__ W1,
                                                   const float* __restrict__ W2,
                                                   const float* __restrict__ linW,
                                                   short* __restrict__ wpk) {
    const int m = blockIdx.x;  // 0..10
    const float* src = (m < 5) ? W1 + (size_t)m * 16384
                               : (m < 10 ? W2 + (size_t)(m - 5) * 16384 : linW);
    for (int f = threadIdx.x; f < 2048; f += 256) {
        int kc = f >> 9;
        int t = (f >> 6) & 7;
        int l = f & 63;
        int kr = kc * 32 + ((l >> 4) << 3);
        int cl = t * 16 + (l & 15);
        short8v hi, lo;
#pragma unroll
        for (int e = 0; e < 8; ++e) {
            float v = src[(size_t)(kr + e) * kH + cl];
            unsigned short h = f2bf(v);
            hi[e] = (short)h;
            lo[e] = (short)f2bf(v - bf2f(h));
        }
        *reinterpret_cast<short8v*>(wpk + (size_t)m * 32768 + (size_t)f * 8) = hi;
        *reinterpret_cast<short8v*>(wpk + (size_t)m * 32768 + 16384 + (size_t)f * 8) = lo;
    }
}

// ---------------- aggregation: agg[n] = sum_{j in N(n)} h[col[j]] ----------------
// one wave per node; 8 edges per round, masked (clamped index, 0/1 weight) so all
// 8 row loads are in flight together; col loads take the scalar path (uniform n).
__global__ __launch_bounds__(256) void gather_kernel(const float* __restrict__ h,
                                                     const int* __restrict__ rowptr,
                                                     const int* __restrict__ col,
                                                     float* __restrict__ agg) {
    const int lane = threadIdx.x & 63;
    const int n = blockIdx.x * 4 + __builtin_amdgcn_readfirstlane(threadIdx.x >> 6);
    if (n >= kN) return;
    const int e0 = rowptr[n], e1 = rowptr[n + 1];
    const float2* __restrict__ hp = reinterpret_cast<const float2*>(h);
    float2* __restrict__ op = reinterpret_cast<float2*>(agg);
    if (e0 == e1) {
        op[(size_t)n * 64 + lane] = make_float2(0.f, 0.f);
        return;
    }
    const int last = e1 - 1;
    float ax = 0.f, ay = 0.f, bx = 0.f, by = 0.f;
    float cx = 0.f, cy = 0.f, dx = 0.f, dy = 0.f;
    for (int e = e0; e < e1; e += 8) {
        int i0, i1, i2, i3, i4, i5, i6, i7;
        float m0, m1, m2, m3, m4, m5, m6, m7;
        {
            int t;
            t = e + 0; m0 = (t <= last) ? 1.f : 0.f; i0 = col[t <= last ? t : last];
            t = e + 1; m1 = (t <= last) ? 1.f : 0.f; i1 = col[t <= last ? t : last];
            t = e + 2; m2 = (t <= last) ? 1.f : 0.f; i2 = col[t <= last ? t : last];
            t = e + 3; m3 = (t <= last) ? 1.f : 0.f; i3 = col[t <= last ? t : last];
            t = e + 4; m4 = (t <= last) ? 1.f : 0.f; i4 = col[t <= last ? t : last];
            t = e + 5; m5 = (t <= last) ? 1.f : 0.f; i5 = col[t <= last ? t : last];
            t = e + 6; m6 = (t <= last) ? 1.f : 0.f; i6 = col[t <= last ? t : last];
            t = e + 7; m7 = (t <= last) ? 1.f : 0.f; i7 = col[t <= last ? t : last];
        }
        float2 v0 = hp[(size_t)i0 * 64 + lane];
        float2 v1 = hp[(size_t)i1 * 64 + lane];
        float2 v2 = hp[(size_t)i2 * 64 + lane];
        float2 v3 = hp[(size_t)i3 * 64 + lane];
        float2 v4 = hp[(size_t)i4 * 64 + lane];
        float2 v5 = hp[(size_t)i5 * 64 + lane];
        float2 v6 = hp[(size_t)i6 * 64 + lane];
        float2 v7 = hp[(size_t)i7 * 64 + lane];
        ax = fmaf(m0, v0.x, ax); ay = fmaf(m0, v0.y, ay);
        bx = fmaf(m1, v1.x, bx); by = fmaf(m1, v1.y, by);
        cx = fmaf(m2, v2.x, cx); cy = fmaf(m2, v2.y, cy);
        dx = fmaf(m3, v3.x, dx); dy = fmaf(m3, v3.y, dy);
        ax = fmaf(m4, v4.x, ax); ay = fmaf(m4, v4.y, ay);
        bx = fmaf(m5, v5.x, bx); by = fmaf(m5, v5.y, by);
        cx = fmaf(m6, v6.x, cx); cy = fmaf(m6, v6.y, cy);
        dx = fmaf(m7, v7.x, dx); dy = fmaf(m7, v7.y, dy);
    }
    op[(size_t)n * 64 + lane] = make_float2((ax + bx) + (cx + dx), (ay + by) + (cy + dy));
}

// ---------------- MFMA GEMM: one wave per 16-row tile, full 128 cols -------------
// MODE 0: A = (1+eps)*A0 + A1, relu->out
// MODE 1: A = A0,              relu->out
// MODE 2: A = A0,              tanh->out
template <int MODE>
__global__ __launch_bounds__(256) void mfma_gemm(const float* __restrict__ A0,
                                                 const float* __restrict__ A1,
                                                 const short* __restrict__ wpk, int mat,
                                                 const float* __restrict__ bias,
                                                 const float* __restrict__ eps_p, int layer,
                                                 float* __restrict__ out) {
    const int lane = threadIdx.x & 63;
    const int tile = blockIdx.x * 4 + (threadIdx.x >> 6);
    if (tile * 16 >= kN) return;
    const int row0 = tile * 16;
    const int m15 = lane & 15;
    const int kg = lane >> 4;  // 0..3
    const int arow = row0 + m15;

    float scale = 1.0f;
    if (MODE == 0) scale = 1.0f + eps_p[layer];

    const short8v* wp = reinterpret_cast<const short8v*>(wpk + (size_t)mat * 32768);

    f32x4 acc[8];
#pragma unroll
    for (int t = 0; t < 8; ++t) acc[t] = (f32x4)0.0f;

#pragma unroll
    for (int kc = 0; kc < 4; ++kc) {
        const float4* ap =
            reinterpret_cast<const float4*>(A0 + (size_t)arow * kH + kc * 32 + kg * 8);
        float4 v0 = ap[0], v1 = ap[1];
        float a[8] = {v0.x, v0.y, v0.z, v0.w, v1.x, v1.y, v1.z, v1.w};
        if (MODE == 0) {
            const float4* bp =
                reinterpret_cast<const float4*>(A1 + (size_t)arow * kH + kc * 32 + kg * 8);
            float4 u0 = bp[0], u1 = bp[1];
            float u[8] = {u0.x, u0.y, u0.z, u0.w, u1.x, u1.y, u1.z, u1.w};
#pragma unroll
            for (int e = 0; e < 8; ++e) a[e] = scale * a[e] + u[e];
        }
        short8v ah, al;
#pragma unroll
        for (int e = 0; e < 8; ++e) {
            unsigned short h = f2bf(a[e]);
            ah[e] = (short)h;
            al[e] = (short)f2bf(a[e] - bf2f(h));
        }
#pragma unroll
        for (int t = 0; t < 8; ++t) {
            int f = (kc * 8 + t) * 64 + lane;
            short8v wh = wp[f];
            short8v wl = wp[2048 + f];
            acc[t] = __builtin_amdgcn_mfma_f32_16x16x32_bf16(al, wh, acc[t], 0, 0, 0);
            acc[t] = __builtin_amdgcn_mfma_f32_16x16x32_bf16(ah, wl, acc[t], 0, 0, 0);
            acc[t] = __builtin_amdgcn_mfma_f32_16x16x32_bf16(ah, wh, acc[t], 0, 0, 0);
        }
    }

    const int orow0 = row0 + kg * 4;
#pragma unroll
    for (int t = 0; t < 8; ++t) {
        int cl = t * 16 + m15;
        float b = bias[cl];
#pragma unroll
        for (int r = 0; r < 4; ++r) {
            float o = acc[t][r] + b;
            if (MODE < 2)
                o = fmaxf(o, 0.f);
            else
                o = tanhf(o);
            out[(size_t)(orow0 + r) * kH + cl] = o;
        }
    }
}

// ---------------- segment mean pool ----------------
__global__ __launch_bounds__(512) void pool_kernel(const float* __restrict__ y,
                                                   const int* __restrict__ gp,
                                                   float* __restrict__ out) {
    __shared__ float part[4][kH];
    const int g = blockIdx.x;
    const int c = threadIdx.x & 127;
    const int q = threadIdx.x >> 7;  // 0..3
    const int s = gp[g], e = gp[g + 1];
    float acc = 0.f;
    for (int r = s + q; r < e; r += 4) acc += y[(size_t)r * kH + c];
    part[q][c] = acc;
    __syncthreads();
    if (q == 0) {
        float v = part[0][c] + part[1][c] + part[2][c] + part[3][c];
        out[g * kH + c] = v / fmaxf((float)(e - s), 1.0f);
    }
}

// ---------------- per-column sums / sums-of-squares ----------------
__global__ __launch_bounds__(256) void stats_kernel(const float* __restrict__ h,
                                                    float* __restrict__ sums,
                                                    float* __restrict__ sumsq) {
    __shared__ float ls[2][kH], lq[2][kH];
    const int tid = threadIdx.x;
    const int c = tid & 127;
    const int y = tid >> 7;
    float s = 0.f, q = 0.f;
    for (int r = blockIdx.x * 2 + y; r < kN; r += gridDim.x * 2) {
        float v = h[(size_t)r * kH + c];
        s += v;
        q += v * v;
    }
    ls[y][c] = s;
    lq[y][c] = q;
    __syncthreads();
    if (y == 0) {
        atomicAdd(&sums[c], ls[0][c] + ls[1][c]);
        atomicAdd(&sumsq[c], lq[0][c] + lq[1][c]);
    }
}

// ---------------- BN (+ optional relu + residual) ----------------
__global__ __launch_bounds__(256) void bn_kernel(const float* __restrict__ h2,
                                                 float* __restrict__ hcur,
                                                 const float* __restrict__ gamma,
                                                 const float* __restrict__ beta,
                                                 const float* __restrict__ sums,
                                                 const float* __restrict__ sumsq,
                                                 int first) {
    const float invN = 1.0f / (float)kN;
    const size_t total = (size_t)kN * (kH / 4);
    const size_t stride = (size_t)gridDim.x * blockDim.x;
    for (size_t i = (size_t)blockIdx.x * blockDim.x + threadIdx.x; i < total; i += stride) {
        int c0 = ((int)(i & 31)) * 4;
        float4 s4 = *reinterpret_cast<const float4*>(sums + c0);
        float4 q4 = *reinterpret_cast<const float4*>(sumsq + c0);
        float4 g4 = *reinterpret_cast<const float4*>(gamma + c0);
        float4 be4 = *reinterpret_cast<const float4*>(beta + c0);
        float4 h4 = reinterpret_cast<const float4*>(h2)[i];
        float o0, o1, o2, o3;
        {
            float mu = s4.x * invN, var = fmaxf(q4.x * invN - mu * mu, 0.f);
            o0 = (h4.x - mu) * rsqrtf(var + kBnEps) * g4.x + be4.x;
        }
        {
            float mu = s4.y * invN, var = fmaxf(q4.y * invN - mu * mu, 0.f);
            o1 = (h4.y - mu) * rsqrtf(var + kBnEps) * g4.y + be4.y;
        }
        {
            float mu = s4.z * invN, var = fmaxf(q4.z * invN - mu * mu, 0.f);
            o2 = (h4.z - mu) * rsqrtf(var + kBnEps) * g4.z + be4.z;
        }
        {
            float mu = s4.w * invN, var = fmaxf(q4.w * invN - mu * mu, 0.f);
            o3 = (h4.w - mu) * rsqrtf(var + kBnEps) * g4.w + be4.w;
        }
        if (first) {
            reinterpret_cast<float4*>(hcur)[i] = make_float4(o0, o1, o2, o3);
        } else {
            float4 p = reinterpret_cast<float4*>(hcur)[i];
            p.x += fmaxf(o0, 0.f);
            p.y += fmaxf(o1, 0.f);
            p.z += fmaxf(o2, 0.f);
            p.w += fmaxf(o3, 0.f);
            reinterpret_cast<float4*>(hcur)[i] = p;
        }
    }
}

// ---------------- launch ----------------
extern "C" void kernel_launch(void* const* d_in, const int* in_sizes, int n_in,
                              void* d_out, int out_size, void* d_ws, size_t ws_size,
                              hipStream_t stream) {
    const float* x     = (const float*)d_in[0];
    const int*   ei    = (const int*)d_in[1];
    const int*   batch = (const int*)d_in[2];
    const float* W1    = (const float*)d_in[3];
    const float* b1    = (const float*)d_in[4];
    const float* W2    = (const float*)d_in[5];
    const float* b2    = (const float*)d_in[6];
    const float* gamma = (const float*)d_in[7];
    const float* beta  = (const float*)d_in[8];
    const float* eps   = (const float*)d_in[9];
    const float* linW  = (const float*)d_in[10];
    const float* linb  = (const float*)d_in[11];
    float* out = (float*)d_out;

    char* ws = (char*)d_ws;
    size_t off = 0;
    auto alloc = [&](size_t bytes) -> char* {
        char* p = ws + off;
        off = (off + bytes + 15) & ~(size_t)15;
        return p;
    };
    float* agg    = (float*)alloc((size_t)kN * kH * 4);  // also holds h2 after GEMM2
    float* hcur   = (float*)alloc((size_t)kN * kH * 4);
    float* hmid   = (float*)alloc((size_t)kN * kH * 4);  // also final tanh output y
    int*   rowptr = (int*)alloc((size_t)(kN + 1) * 4);
    int*   deg    = (int*)alloc((size_t)kN * 4);
    int*   local  = (int*)alloc((size_t)kN * 4);
    int*   cursor = (int*)alloc((size_t)kN * 4);
    int*   bsum   = (int*)alloc((size_t)128 * 4);
    int*   colidx = (int*)alloc((size_t)kE * 4);
    float* stats  = (float*)alloc((size_t)kL * 256 * 4); // per layer: [sums 128][sumsq 128]
    int*   gp     = (int*)alloc((size_t)(kG + 1) * 4);
    short* wpk    = (short*)alloc((size_t)11 * 32768 * 2);  // 11 matrices, hi+lo planes

    const int* srcp = ei;       // edge_index[0] (source)
    const int* dstp = ei + kE;  // edge_index[1] (target)

    hipMemsetAsync(deg, 0, (size_t)kN * 4, stream);
    hipMemsetAsync(stats, 0, (size_t)kL * 256 * 4, stream);

    hist_kernel<<<(kE + 255) / 256, 256, 0, stream>>>(dstp, deg);
    scan1_kernel<<<kScanG, kScanB, 0, stream>>>(deg, local, bsum);
    scan2_kernel<<<1, 128, 0, stream>>>(bsum);
    scan3_kernel<<<kScanG, kScanB, 0, stream>>>(local, bsum, rowptr, cursor);
    scatter_kernel<<<(kE + 255) / 256, 256, 0, stream>>>(srcp, dstp, cursor, colidx);
    gp_kernel<<<(kN + 255) / 256, 256, 0, stream>>>(batch, gp);
    pack_kernel<<<11, 256, 0, stream>>>(W1, W2, linW, wpk);

    const int gemm_grid = (kN / 16 + 3) / 4;  // 3125 tiles -> 782 blocks
    for (int l = 0; l < kL; ++l) {
        const float* hin = (l == 0) ? x : hcur;
        gather_kernel<<<(kN + 3) / 4, 256, 0, stream>>>(hin, rowptr, colidx, agg);
        mfma_gemm<0><<<gemm_grid, 256, 0, stream>>>(hin, agg, wpk, l, b1 + (size_t)l * kH,
                                                    eps, l, hmid);
        mfma_gemm<1><<<gemm_grid, 256, 0, stream>>>(hmid, nullptr, wpk, 5 + l,
                                                    b2 + (size_t)l * kH, nullptr, 0, agg);
        stats_kernel<<<512, 256, 0, stream>>>(agg, stats + l * 256, stats + l * 256 + 128);
        bn_kernel<<<2048, 256, 0, stream>>>(agg, hcur, gamma + (size_t)l * kH,
                                            beta + (size_t)l * kH, stats + l * 256,
                                            stats + l * 256 + 128, l == 0 ? 1 : 0);
    }
    mfma_gemm<2><<<gemm_grid, 256, 0, stream>>>(hcur, nullptr, wpk, 10, linb, nullptr, 0, hmid);
    pool_kernel<<<kG, 512, 0, stream>>>(hmid, gp, out);
}

// Round 6
// 691.082 us; speedup vs baseline: 2.4006x; 1.2231x over previous
//
#include <hip/hip_runtime.h>
#include <cstddef>

// GIN forward on MI355X — round 6:
//  (a) two-phase segment pool (was 54.9us at 4% occupancy -> ~8us)
//  (b) bf16 gather: bn_kernel co-writes a bf16 mirror of node features; gather reads
//      256B/row instead of 512B (traffic-bound per R5 counters: 176MB FETCH, 45% HBM).
//      agg stays fp32; MFMA path already consumes bf16 hi+lo, BN renormalizes.

namespace {
constexpr int kN = 50000;
constexpr int kE = 800000;
constexpr int kH = 128;
constexpr int kL = 5;
constexpr int kG = 64;
constexpr float kBnEps = 1e-5f;
constexpr int kScanB = 512;
constexpr int kScanG = (kN + kScanB - 1) / kScanB;  // 98
}

typedef __attribute__((ext_vector_type(8))) short short8v;
typedef __attribute__((ext_vector_type(4))) float f32x4;

__device__ inline unsigned short f2bf(float f) {
    unsigned int u = __float_as_uint(f);
    unsigned int r = (u + 0x7fffu + ((u >> 16) & 1u)) >> 16;  // round-to-nearest-even
    return (unsigned short)r;
}
__device__ inline float bf2f(unsigned int h16) {
    return __uint_as_float(h16 << 16);
}

// ---------------- graph build (once per call) ----------------

__global__ void hist_kernel(const int* __restrict__ dst, int* __restrict__ deg) {
    int i = blockIdx.x * blockDim.x + threadIdx.x;
    if (i < kE) atomicAdd(&deg[dst[i]], 1);
}

__global__ __launch_bounds__(kScanB) void scan1_kernel(const int* __restrict__ deg,
                                                       int* __restrict__ local,
                                                       int* __restrict__ bsum) {
    const int i = blockIdx.x * kScanB + threadIdx.x;
    const int lane = threadIdx.x & 63;
    const int wid = threadIdx.x >> 6;  // 0..7
    int v = (i < kN) ? deg[i] : 0;
    int s = v;
#pragma unroll
    for (int d = 1; d < 64; d <<= 1) {
        int t = __shfl_up(s, d);
        if (lane >= d) s += t;
    }
    __shared__ int wsum[8];
    if (lane == 63) wsum[wid] = s;
    __syncthreads();
    if (threadIdx.x < 8) {
        int w = wsum[threadIdx.x];
#pragma unroll
        for (int d = 1; d < 8; d <<= 1) {
            int t = __shfl_up(w, d);
            if (lane >= d) w += t;
        }
        wsum[threadIdx.x] = w;
    }
    __syncthreads();
    int woff = (wid == 0) ? 0 : wsum[wid - 1];
    int incl = s + woff;
    if (i < kN) local[i] = incl - v;
    if (threadIdx.x == kScanB - 1) bsum[blockIdx.x] = incl;
}

__global__ void scan2_kernel(int* __restrict__ bsum) {
    const int t = threadIdx.x;
    const int lane = t & 63;
    const int wid = t >> 6;  // 0..1
    int v = (t < kScanG) ? bsum[t] : 0;
    int s = v;
#pragma unroll
    for (int d = 1; d < 64; d <<= 1) {
        int u = __shfl_up(s, d);
        if (lane >= d) s += u;
    }
    __shared__ int ws[2];
    if (lane == 63) ws[wid] = s;
    __syncthreads();
    int incl = s + ((wid == 1) ? ws[0] : 0);
    if (t < kScanG) bsum[t] = incl - v;
}

__global__ __launch_bounds__(kScanB) void scan3_kernel(const int* __restrict__ local,
                                                       const int* __restrict__ bsum,
                                                       int* __restrict__ rowptr,
                                                       int* __restrict__ cursor) {
    const int i = blockIdx.x * kScanB + threadIdx.x;
    if (i < kN) {
        int v = local[i] + bsum[blockIdx.x];
        rowptr[i] = v;
        cursor[i] = v;
    }
    if (i == 0) rowptr[kN] = kE;
}

__global__ void scatter_kernel(const int* __restrict__ src, const int* __restrict__ dst,
                               int* __restrict__ cursor, int* __restrict__ col) {
    int i = blockIdx.x * blockDim.x + threadIdx.x;
    if (i < kE) {
        int p = atomicAdd(&cursor[dst[i]], 1);
        col[p] = src[i];
    }
}

// batch is sorted: gp[g] = first row index of graph g, gp[kG] = kN. No atomics.
__global__ void gp_kernel(const int* __restrict__ batch, int* __restrict__ gp) {
    int i = blockIdx.x * blockDim.x + threadIdx.x;
    if (i >= kN) return;
    int b = batch[i];
    if (i == 0) {
        for (int g = 0; g <= b; ++g) gp[g] = 0;
    } else {
        int p = batch[i - 1];
        for (int g = p; g < b; ++g) gp[g + 1] = i;
    }
    if (i == kN - 1) {
        for (int g = b; g < kG; ++g) gp[g + 1] = kN;
    }
}

// ---------------- weight pre-pack: 11 matrices -> MFMA fragment order, hi/lo bf16 ----------
__global__ __launch_bounds__(256) void pack_kernel(const float* __restrict__ W1,
                                                   const float* __restrict__ W2,
                                                   const float* __restrict__ linW,
                                                   short* __restrict__ wpk) {
    const int m = blockIdx.x;  // 0..10
    const float* src = (m < 5) ? W1 + (size_t)m * 16384
                               : (m < 10 ? W2 + (size_t)(m - 5) * 16384 : linW);
    for (int f = threadIdx.x; f < 2048; f += 256) {
        int kc = f >> 9;
        int t = (f >> 6) & 7;
        int l = f & 63;
        int kr = kc * 32 + ((l >> 4) << 3);
        int cl = t * 16 + (l & 15);
        short8v hi, lo;
#pragma unroll
        for (int e = 0; e < 8; ++e) {
            float v = src[(size_t)(kr + e) * kH + cl];
            unsigned short h = f2bf(v);
            hi[e] = (short)h;
            lo[e] = (short)f2bf(v - bf2f(h));
        }
        *reinterpret_cast<short8v*>(wpk + (size_t)m * 32768 + (size_t)f * 8) = hi;
        *reinterpret_cast<short8v*>(wpk + (size_t)m * 32768 + 16384 + (size_t)f * 8) = lo;
    }
}

// ---------------- x -> bf16 mirror (layer 0 only) ----------------
__global__ __launch_bounds__(256) void conv_kernel(const float* __restrict__ x,
                                                   unsigned int* __restrict__ hb) {
    int i = blockIdx.x * blockDim.x + threadIdx.x;  // over kN*32 float4s
    if (i >= kN * (kH / 4)) return;
    float4 v = reinterpret_cast<const float4*>(x)[i];
    unsigned int p01 = (unsigned int)f2bf(v.x) | ((unsigned int)f2bf(v.y) << 16);
    unsigned int p23 = (unsigned int)f2bf(v.z) | ((unsigned int)f2bf(v.w) << 16);
    hb[i * 2] = p01;
    hb[i * 2 + 1] = p23;
}

// ---------------- aggregation: agg[n] = sum_{j in N(n)} hb[col[j]] (bf16 rows) --------
// one wave per node; 8 edges per round, masked; per-lane 4B (2 bf16) per row.
__global__ __launch_bounds__(256) void gather_kernel(const unsigned int* __restrict__ hb,
                                                     const int* __restrict__ rowptr,
                                                     const int* __restrict__ col,
                                                     float* __restrict__ agg) {
    const int lane = threadIdx.x & 63;
    const int n = blockIdx.x * 4 + __builtin_amdgcn_readfirstlane(threadIdx.x >> 6);
    if (n >= kN) return;
    const int e0 = rowptr[n], e1 = rowptr[n + 1];
    float2* __restrict__ op = reinterpret_cast<float2*>(agg);
    if (e0 == e1) {
        op[(size_t)n * 64 + lane] = make_float2(0.f, 0.f);
        return;
    }
    const int last = e1 - 1;
    float ax = 0.f, ay = 0.f, bx = 0.f, by = 0.f;
    float cx = 0.f, cy = 0.f, dx = 0.f, dy = 0.f;
    for (int e = e0; e < e1; e += 8) {
        int i0, i1, i2, i3, i4, i5, i6, i7;
        float m0, m1, m2, m3, m4, m5, m6, m7;
        {
            int t;
            t = e + 0; m0 = (t <= last) ? 1.f : 0.f; i0 = col[t <= last ? t : last];
            t = e + 1; m1 = (t <= last) ? 1.f : 0.f; i1 = col[t <= last ? t : last];
            t = e + 2; m2 = (t <= last) ? 1.f : 0.f; i2 = col[t <= last ? t : last];
            t = e + 3; m3 = (t <= last) ? 1.f : 0.f; i3 = col[t <= last ? t : last];
            t = e + 4; m4 = (t <= last) ? 1.f : 0.f; i4 = col[t <= last ? t : last];
            t = e + 5; m5 = (t <= last) ? 1.f : 0.f; i5 = col[t <= last ? t : last];
            t = e + 6; m6 = (t <= last) ? 1.f : 0.f; i6 = col[t <= last ? t : last];
            t = e + 7; m7 = (t <= last) ? 1.f : 0.f; i7 = col[t <= last ? t : last];
        }
        unsigned int u0 = hb[(size_t)i0 * 64 + lane];
        unsigned int u1 = hb[(size_t)i1 * 64 + lane];
        unsigned int u2 = hb[(size_t)i2 * 64 + lane];
        unsigned int u3 = hb[(size_t)i3 * 64 + lane];
        unsigned int u4 = hb[(size_t)i4 * 64 + lane];
        unsigned int u5 = hb[(size_t)i5 * 64 + lane];
        unsigned int u6 = hb[(size_t)i6 * 64 + lane];
        unsigned int u7 = hb[(size_t)i7 * 64 + lane];
        ax = fmaf(m0, bf2f(u0 & 0xffffu), ax); ay = fmaf(m0, bf2f(u0 >> 16), ay);
        bx = fmaf(m1, bf2f(u1 & 0xffffu), bx); by = fmaf(m1, bf2f(u1 >> 16), by);
        cx = fmaf(m2, bf2f(u2 & 0xffffu), cx); cy = fmaf(m2, bf2f(u2 >> 16), cy);
        dx = fmaf(m3, bf2f(u3 & 0xffffu), dx); dy = fmaf(m3, bf2f(u3 >> 16), dy);
        ax = fmaf(m4, bf2f(u4 & 0xffffu), ax); ay = fmaf(m4, bf2f(u4 >> 16), ay);
        bx = fmaf(m5, bf2f(u5 & 0xffffu), bx); by = fmaf(m5, bf2f(u5 >> 16), by);
        cx = fmaf(m6, bf2f(u6 & 0xffffu), cx); cy = fmaf(m6, bf2f(u6 >> 16), cy);
        dx = fmaf(m7, bf2f(u7 & 0xffffu), dx); dy = fmaf(m7, bf2f(u7 >> 16), dy);
    }
    op[(size_t)n * 64 + lane] = make_float2((ax + bx) + (cx + dx), (ay + by) + (cy + dy));
}

// ---------------- MFMA GEMM: one wave per 16-row tile, full 128 cols -------------
// MODE 0: A = (1+eps)*A0 + A1, relu->out
// MODE 1: A = A0,              relu->out
// MODE 2: A = A0,              tanh->out
template <int MODE>
__global__ __launch_bounds__(256) void mfma_gemm(const float* __restrict__ A0,
                                                 const float* __restrict__ A1,
                                                 const short* __restrict__ wpk, int mat,
                                                 const float* __restrict__ bias,
                                                 const float* __restrict__ eps_p, int layer,
                                                 float* __restrict__ out) {
    const int lane = threadIdx.x & 63;
    const int tile = blockIdx.x * 4 + (threadIdx.x >> 6);
    if (tile * 16 >= kN) return;
    const int row0 = tile * 16;
    const int m15 = lane & 15;
    const int kg = lane >> 4;  // 0..3
    const int arow = row0 + m15;

    float scale = 1.0f;
    if (MODE == 0) scale = 1.0f + eps_p[layer];

    const short8v* wp = reinterpret_cast<const short8v*>(wpk + (size_t)mat * 32768);

    f32x4 acc[8];
#pragma unroll
    for (int t = 0; t < 8; ++t) acc[t] = (f32x4)0.0f;

#pragma unroll
    for (int kc = 0; kc < 4; ++kc) {
        const float4* ap =
            reinterpret_cast<const float4*>(A0 + (size_t)arow * kH + kc * 32 + kg * 8);
        float4 v0 = ap[0], v1 = ap[1];
        float a[8] = {v0.x, v0.y, v0.z, v0.w, v1.x, v1.y, v1.z, v1.w};
        if (MODE == 0) {
            const float4* bp =
                reinterpret_cast<const float4*>(A1 + (size_t)arow * kH + kc * 32 + kg * 8);
            float4 u0 = bp[0], u1 = bp[1];
            float u[8] = {u0.x, u0.y, u0.z, u0.w, u1.x, u1.y, u1.z, u1.w};
#pragma unroll
            for (int e = 0; e < 8; ++e) a[e] = scale * a[e] + u[e];
        }
        short8v ah, al;
#pragma unroll
        for (int e = 0; e < 8; ++e) {
            unsigned short h = f2bf(a[e]);
            ah[e] = (short)h;
            al[e] = (short)f2bf(a[e] - bf2f(h));
        }
#pragma unroll
        for (int t = 0; t < 8; ++t) {
            int f = (kc * 8 + t) * 64 + lane;
            short8v wh = wp[f];
            short8v wl = wp[2048 + f];
            acc[t] = __builtin_amdgcn_mfma_f32_16x16x32_bf16(al, wh, acc[t], 0, 0, 0);
            acc[t] = __builtin_amdgcn_mfma_f32_16x16x32_bf16(ah, wl, acc[t], 0, 0, 0);
            acc[t] = __builtin_amdgcn_mfma_f32_16x16x32_bf16(ah, wh, acc[t], 0, 0, 0);
        }
    }

    const int orow0 = row0 + kg * 4;
#pragma unroll
    for (int t = 0; t < 8; ++t) {
        int cl = t * 16 + m15;
        float b = bias[cl];
#pragma unroll
        for (int r = 0; r < 4; ++r) {
            float o = acc[t][r] + b;
            if (MODE < 2)
                o = fmaxf(o, 0.f);
            else
                o = tanhf(o);
            out[(size_t)(orow0 + r) * kH + cl] = o;
        }
    }
}

// ---------------- two-phase segment mean pool ----------------
__global__ __launch_bounds__(256) void pool1_kernel(const float* __restrict__ y,
                                                    const int* __restrict__ gp,
                                                    float* __restrict__ partial) {
    const int g = blockIdx.x >> 4;
    const int s = blockIdx.x & 15;
    const int c = threadIdx.x & 127;
    const int q = threadIdx.x >> 7;  // 0..1
    const int rs = gp[g], re = gp[g + 1];
    float acc = 0.f;
    for (int r = rs + s * 2 + q; r < re; r += 32) acc += y[(size_t)r * kH + c];
    __shared__ float part[2][kH];
    part[q][c] = acc;
    __syncthreads();
    if (q == 0) partial[(size_t)blockIdx.x * kH + c] = part[0][c] + part[1][c];
}

__global__ void pool2_kernel(const float* __restrict__ partial, const int* __restrict__ gp,
                             float* __restrict__ out) {
    const int g = blockIdx.x;
    const int c = threadIdx.x;  // 128
    float v = 0.f;
#pragma unroll
    for (int s = 0; s < 16; ++s) v += partial[(size_t)((g << 4) + s) * kH + c];
    out[g * kH + c] = v / fmaxf((float)(gp[g + 1] - gp[g]), 1.0f);
}

// ---------------- per-column sums / sums-of-squares ----------------
__global__ __launch_bounds__(256) void stats_kernel(const float* __restrict__ h,
                                                    float* __restrict__ sums,
                                                    float* __restrict__ sumsq) {
    __shared__ float ls[2][kH], lq[2][kH];
    const int tid = threadIdx.x;
    const int c = tid & 127;
    const int y = tid >> 7;
    float s = 0.f, q = 0.f;
    for (int r = blockIdx.x * 2 + y; r < kN; r += gridDim.x * 2) {
        float v = h[(size_t)r * kH + c];
        s += v;
        q += v * v;
    }
    ls[y][c] = s;
    lq[y][c] = q;
    __syncthreads();
    if (y == 0) {
        atomicAdd(&sums[c], ls[0][c] + ls[1][c]);
        atomicAdd(&sumsq[c], lq[0][c] + lq[1][c]);
    }
}

// ---------------- BN (+ optional relu + residual) + bf16 mirror store ----------------
__global__ __launch_bounds__(256) void bn_kernel(const float* __restrict__ h2,
                                                 float* __restrict__ hcur,
                                                 unsigned int* __restrict__ hb,
                                                 const float* __restrict__ gamma,
                                                 const float* __restrict__ beta,
                                                 const float* __restrict__ sums,
                                                 const float* __restrict__ sumsq,
                                                 int first, int last) {
    const float invN = 1.0f / (float)kN;
    const size_t total = (size_t)kN * (kH / 4);
    const size_t stride = (size_t)gridDim.x * blockDim.x;
    for (size_t i = (size_t)blockIdx.x * blockDim.x + threadIdx.x; i < total; i += stride) {
        int c0 = ((int)(i & 31)) * 4;
        float4 s4 = *reinterpret_cast<const float4*>(sums + c0);
        float4 q4 = *reinterpret_cast<const float4*>(sumsq + c0);
        float4 g4 = *reinterpret_cast<const float4*>(gamma + c0);
        float4 be4 = *reinterpret_cast<const float4*>(beta + c0);
        float4 h4 = reinterpret_cast<const float4*>(h2)[i];
        float o0, o1, o2, o3;
        {
            float mu = s4.x * invN, var = fmaxf(q4.x * invN - mu * mu, 0.f);
            o0 = (h4.x - mu) * rsqrtf(var + kBnEps) * g4.x + be4.x;
        }
        {
            float mu = s4.y * invN, var = fmaxf(q4.y * invN - mu * mu, 0.f);
            o1 = (h4.y - mu) * rsqrtf(var + kBnEps) * g4.y + be4.y;
        }
        {
            float mu = s4.z * invN, var = fmaxf(q4.z * invN - mu * mu, 0.f);
            o2 = (h4.z - mu) * rsqrtf(var + kBnEps) * g4.z + be4.z;
        }
        {
            float mu = s4.w * invN, var = fmaxf(q4.w * invN - mu * mu, 0.f);
            o3 = (h4.w - mu) * rsqrtf(var + kBnEps) * g4.w + be4.w;
        }
        float4 r;
        if (first) {
            r = make_float4(o0, o1, o2, o3);
        } else {
            float4 p = reinterpret_cast<const float4*>(hcur)[i];
            r = make_float4(p.x + fmaxf(o0, 0.f), p.y + fmaxf(o1, 0.f),
                            p.z + fmaxf(o2, 0.f), p.w + fmaxf(o3, 0.f));
        }
        reinterpret_cast<float4*>(hcur)[i] = r;
        if (!last) {
            unsigned int p01 = (unsigned int)f2bf(r.x) | ((unsigned int)f2bf(r.y) << 16);
            unsigned int p23 = (unsigned int)f2bf(r.z) | ((unsigned int)f2bf(r.w) << 16);
            hb[i * 2] = p01;
            hb[i * 2 + 1] = p23;
        }
    }
}

// ---------------- launch ----------------
extern "C" void kernel_launch(void* const* d_in, const int* in_sizes, int n_in,
                              void* d_out, int out_size, void* d_ws, size_t ws_size,
                              hipStream_t stream) {
    const float* x     = (const float*)d_in[0];
    const int*   ei    = (const int*)d_in[1];
    const int*   batch = (const int*)d_in[2];
    const float* W1    = (const float*)d_in[3];
    const float* b1    = (const float*)d_in[4];
    const float* W2    = (const float*)d_in[5];
    const float* b2    = (const float*)d_in[6];
    const float* gamma = (const float*)d_in[7];
    const float* beta  = (const float*)d_in[8];
    const float* eps   = (const float*)d_in[9];
    const float* linW  = (const float*)d_in[10];
    const float* linb  = (const float*)d_in[11];
    float* out = (float*)d_out;

    char* ws = (char*)d_ws;
    size_t off = 0;
    auto alloc = [&](size_t bytes) -> char* {
        char* p = ws + off;
        off = (off + bytes + 15) & ~(size_t)15;
        return p;
    };
    float* agg    = (float*)alloc((size_t)kN * kH * 4);  // h2 after GEMM2; partial during pool
    float* hcur   = (float*)alloc((size_t)kN * kH * 4);
    float* hmid   = (float*)alloc((size_t)kN * kH * 4);  // also final tanh output y
    unsigned int* hb = (unsigned int*)alloc((size_t)kN * kH * 2);  // bf16 mirror
    int*   rowptr = (int*)alloc((size_t)(kN + 1) * 4);
    int*   deg    = (int*)alloc((size_t)kN * 4);
    int*   local  = (int*)alloc((size_t)kN * 4);
    int*   cursor = (int*)alloc((size_t)kN * 4);
    int*   bsum   = (int*)alloc((size_t)128 * 4);
    int*   colidx = (int*)alloc((size_t)kE * 4);
    float* stats  = (float*)alloc((size_t)kL * 256 * 4);
    int*   gp     = (int*)alloc((size_t)(kG + 1) * 4);
    short* wpk    = (short*)alloc((size_t)11 * 32768 * 2);

    float* partial = agg;  // [kG*16][kH], only live during pooling (agg free then)

    const int* srcp = ei;       // edge_index[0] (source)
    const int* dstp = ei + kE;  // edge_index[1] (target)

    hipMemsetAsync(deg, 0, (size_t)kN * 4, stream);
    hipMemsetAsync(stats, 0, (size_t)kL * 256 * 4, stream);

    hist_kernel<<<(kE + 255) / 256, 256, 0, stream>>>(dstp, deg);
    scan1_kernel<<<kScanG, kScanB, 0, stream>>>(deg, local, bsum);
    scan2_kernel<<<1, 128, 0, stream>>>(bsum);
    scan3_kernel<<<kScanG, kScanB, 0, stream>>>(local, bsum, rowptr, cursor);
    scatter_kernel<<<(kE + 255) / 256, 256, 0, stream>>>(srcp, dstp, cursor, colidx);
    gp_kernel<<<(kN + 255) / 256, 256, 0, stream>>>(batch, gp);
    pack_kernel<<<11, 256, 0, stream>>>(W1, W2, linW, wpk);
    conv_kernel<<<(kN * (kH / 4) + 255) / 256, 256, 0, stream>>>(x, hb);

    const int gemm_grid = (kN / 16 + 3) / 4;  // 3125 tiles -> 782 blocks
    for (int l = 0; l < kL; ++l) {
        const float* hin = (l == 0) ? x : hcur;
        gather_kernel<<<(kN + 3) / 4, 256, 0, stream>>>(hb, rowptr, colidx, agg);
        mfma_gemm<0><<<gemm_grid, 256, 0, stream>>>(hin, agg, wpk, l, b1 + (size_t)l * kH,
                                                    eps, l, hmid);
        mfma_gemm<1><<<gemm_grid, 256, 0, stream>>>(hmid, nullptr, wpk, 5 + l,
                                                    b2 + (size_t)l * kH, nullptr, 0, agg);
        stats_kernel<<<512, 256, 0, stream>>>(agg, stats + l * 256, stats + l * 256 + 128);
        bn_kernel<<<2048, 256, 0, stream>>>(agg, hcur, hb, gamma + (size_t)l * kH,
                                            beta + (size_t)l * kH, stats + l * 256,
                                            stats + l * 256 + 128, l == 0 ? 1 : 0,
                                            l == kL - 1 ? 1 : 0);
    }
    mfma_gemm<2><<<gemm_grid, 256, 0, stream>>>(hcur, nullptr, wpk, 10, linb, nullptr, 0, hmid);
    pool1_kernel<<<kG * 16, 256, 0, stream>>>(hmid, gp, partial);
    pool2_kernel<<<kG, kH, 0, stream>>>(partial, gp, out);
}

// Round 7
// 524.001 us; speedup vs baseline: 3.1661x; 1.3189x over previous
//
#include <hip/hip_runtime.h>
#include <cstddef>

// GIN forward on MI355X — round 7:
//  (a) atomic-free CSR build: 2-pass bucket sort (49 buckets of 1024 dst each) with LDS
//      histograms/cursors. Kills hist+scatter's 800k+800k device atomics (~100MB of
//      memory-side 64B line RMWs, ~90us).
//  (b) BN stats fused into GEMM2 epilogue (shfl_xor row-reduce + LDS + per-block partial,
//      64-block reducer). Kills 5x stats_kernel (~65us).

namespace {
constexpr int kN = 50000;
constexpr int kE = 800000;
constexpr int kH = 128;
constexpr int kL = 5;
constexpr int kG = 64;
constexpr float kBnEps = 1e-5f;
constexpr int kEPB = 1024;                      // edges per pass-1 block
constexpr int kG1 = (kE + kEPB - 1) / kEPB;     // 782
constexpr int kB = 49;                          // buckets: dst>>10, dst<50000
constexpr int kM = kB * kG1;                    // 38318 scan length
constexpr int kGemmGrid = (kN / 16 + 3) / 4;    // 782
}

typedef __attribute__((ext_vector_type(8))) short short8v;
typedef __attribute__((ext_vector_type(4))) float f32x4;

__device__ inline unsigned short f2bf(float f) {
    unsigned int u = __float_as_uint(f);
    unsigned int r = (u + 0x7fffu + ((u >> 16) & 1u)) >> 16;  // round-to-nearest-even
    return (unsigned short)r;
}
__device__ inline float bf2f(unsigned int h16) {
    return __uint_as_float(h16 << 16);
}

// ---------------- CSR build, pass 1a: per-block bucket histogram ----------------
__global__ __launch_bounds__(256) void part1a_kernel(const int* __restrict__ dst,
                                                     int* __restrict__ bh) {
    __shared__ int hist[kB];
    const int tid = threadIdx.x;
    if (tid < kB) hist[tid] = 0;
    __syncthreads();
    const int base = blockIdx.x * kEPB;
    for (int i = tid; i < kEPB; i += 256) {
        int e = base + i;
        if (e < kE) atomicAdd(&hist[dst[e] >> 10], 1);
    }
    __syncthreads();
    if (tid < kB) bh[tid * kG1 + blockIdx.x] = hist[tid];  // bucket-major for flat scan
}

// ---------------- parameterized 3-phase exclusive scan ----------------
__global__ __launch_bounds__(512) void scanP1_kernel(const int* __restrict__ in,
                                                     int* __restrict__ loc,
                                                     int* __restrict__ bsum, int n) {
    const int i = blockIdx.x * 512 + threadIdx.x;
    const int lane = threadIdx.x & 63;
    const int wid = threadIdx.x >> 6;
    int v = (i < n) ? in[i] : 0;
    int s = v;
#pragma unroll
    for (int d = 1; d < 64; d <<= 1) {
        int t = __shfl_up(s, d);
        if (lane >= d) s += t;
    }
    __shared__ int wsum[8];
    if (lane == 63) wsum[wid] = s;
    __syncthreads();
    if (threadIdx.x < 8) {
        int w = wsum[threadIdx.x];
#pragma unroll
        for (int d = 1; d < 8; d <<= 1) {
            int t = __shfl_up(w, d);
            if (lane >= d) w += t;
        }
        wsum[threadIdx.x] = w;
    }
    __syncthreads();
    int woff = (wid == 0) ? 0 : wsum[wid - 1];
    int incl = s + woff;
    if (i < n) loc[i] = incl - v;
    if (threadIdx.x == 511) bsum[blockIdx.x] = incl;
}

__global__ void scanP2_kernel(int* __restrict__ bsum, int nb) {
    const int t = threadIdx.x;  // 128
    const int lane = t & 63;
    const int wid = t >> 6;
    int v = (t < nb) ? bsum[t] : 0;
    int s = v;
#pragma unroll
    for (int d = 1; d < 64; d <<= 1) {
        int u = __shfl_up(s, d);
        if (lane >= d) s += u;
    }
    __shared__ int ws[2];
    if (lane == 63) ws[wid] = s;
    __syncthreads();
    int incl = s + ((wid == 1) ? ws[0] : 0);
    if (t < nb) bsum[t] = incl - v;
}

__global__ __launch_bounds__(512) void scanP3_kernel(const int* __restrict__ loc,
                                                     const int* __restrict__ bsum,
                                                     int* __restrict__ outp, int n) {
    const int i = blockIdx.x * 512 + threadIdx.x;
    if (i < n) outp[i] = loc[i] + bsum[blockIdx.x];
}

// ---------------- CSR build, pass 1b: partition edges into buckets ----------------
__global__ __launch_bounds__(256) void part1b_kernel(const int* __restrict__ src,
                                                     const int* __restrict__ dst,
                                                     const int* __restrict__ bhex,
                                                     unsigned int* __restrict__ part) {
    __shared__ int cur[kB];
    const int tid = threadIdx.x;
    if (tid < kB) cur[tid] = bhex[tid * kG1 + blockIdx.x];
    __syncthreads();
    const int base = blockIdx.x * kEPB;
    for (int i = tid; i < kEPB; i += 256) {
        int e = base + i;
        if (e < kE) {
            unsigned int d = (unsigned int)dst[e];
            unsigned int s = (unsigned int)src[e];
            int p = atomicAdd(&cur[d >> 10], 1);
            part[p] = (d << 16) | s;
        }
    }
}

// ---------------- CSR build, pass 2: per-bucket local CSR (rowptr + col) ----------------
__global__ __launch_bounds__(1024) void bucket_kernel(const unsigned int* __restrict__ part,
                                                      const int* __restrict__ bhex,
                                                      int* __restrict__ rowptr,
                                                      int* __restrict__ col) {
    const int b = blockIdx.x;  // 0..48
    const int tid = threadIdx.x;
    const int lane = tid & 63;
    const int wid = tid >> 6;  // 0..15
    const int bstart = bhex[b * kG1];
    const int bend = (b == kB - 1) ? kE : bhex[(b + 1) * kG1];
    __shared__ int lhist[1024];
    __shared__ int wsum[16];
    lhist[tid] = 0;
    __syncthreads();
    for (int e = bstart + tid; e < bend; e += 1024)
        atomicAdd(&lhist[part[e] >> 16 & 1023], 1);
    __syncthreads();
    int v = lhist[tid];
    int s = v;
#pragma unroll
    for (int d = 1; d < 64; d <<= 1) {
        int t = __shfl_up(s, d);
        if (lane >= d) s += t;
    }
    if (lane == 63) wsum[wid] = s;
    __syncthreads();
    if (tid < 16) {
        int w = wsum[tid];
#pragma unroll
        for (int d = 1; d < 16; d <<= 1) {
            int t = __shfl_up(w, d);
            if (lane >= d) w += t;
        }
        wsum[tid] = w;
    }
    __syncthreads();
    int excl = s - v + ((wid == 0) ? 0 : wsum[wid - 1]);
    const int d = (b << 10) + tid;
    if (d < kN) rowptr[d] = bstart + excl;
    __syncthreads();
    lhist[tid] = bstart + excl;  // cursor
    __syncthreads();
    for (int e = bstart + tid; e < bend; e += 1024) {
        unsigned int pv = part[e];
        int p = atomicAdd(&lhist[pv >> 16 & 1023], 1);
        col[p] = (int)(pv & 0xffffu);
    }
    if (b == kB - 1 && tid == 0) rowptr[kN] = kE;
}

// batch is sorted: gp[g] = first row index of graph g, gp[kG] = kN. No atomics.
__global__ void gp_kernel(const int* __restrict__ batch, int* __restrict__ gp) {
    int i = blockIdx.x * blockDim.x + threadIdx.x;
    if (i >= kN) return;
    int b = batch[i];
    if (i == 0) {
        for (int g = 0; g <= b; ++g) gp[g] = 0;
    } else {
        int p = batch[i - 1];
        for (int g = p; g < b; ++g) gp[g + 1] = i;
    }
    if (i == kN - 1) {
        for (int g = b; g < kG; ++g) gp[g + 1] = kN;
    }
}

// ---------------- weight pre-pack: 11 matrices -> MFMA fragment order, hi/lo bf16 ----------
__global__ __launch_bounds__(256) void pack_kernel(const float* __restrict__ W1,
                                                   const float* __restrict__ W2,
                                                   const float* __restrict__ linW,
                                                   short* __restrict__ wpk) {
    const int m = blockIdx.x;  // 0..10
    const float* src = (m < 5) ? W1 + (size_t)m * 16384
                               : (m < 10 ? W2 + (size_t)(m - 5) * 16384 : linW);
    for (int f = threadIdx.x; f < 2048; f += 256) {
        int kc = f >> 9;
        int t = (f >> 6) & 7;
        int l = f & 63;
        int kr = kc * 32 + ((l >> 4) << 3);
        int cl = t * 16 + (l & 15);
        short8v hi, lo;
#pragma unroll
        for (int e = 0; e < 8; ++e) {
            float v = src[(size_t)(kr + e) * kH + cl];
            unsigned short h = f2bf(v);
            hi[e] = (short)h;
            lo[e] = (short)f2bf(v - bf2f(h));
        }
        *reinterpret_cast<short8v*>(wpk + (size_t)m * 32768 + (size_t)f * 8) = hi;
        *reinterpret_cast<short8v*>(wpk + (size_t)m * 32768 + 16384 + (size_t)f * 8) = lo;
    }
}

// ---------------- x -> bf16 mirror (layer 0 only) ----------------
__global__ __launch_bounds__(256) void conv_kernel(const float* __restrict__ x,
                                                   unsigned int* __restrict__ hb) {
    int i = blockIdx.x * blockDim.x + threadIdx.x;  // over kN*32 float4s
    if (i >= kN * (kH / 4)) return;
    float4 v = reinterpret_cast<const float4*>(x)[i];
    unsigned int p01 = (unsigned int)f2bf(v.x) | ((unsigned int)f2bf(v.y) << 16);
    unsigned int p23 = (unsigned int)f2bf(v.z) | ((unsigned int)f2bf(v.w) << 16);
    hb[i * 2] = p01;
    hb[i * 2 + 1] = p23;
}

// ---------------- aggregation: agg[n] = sum_{j in N(n)} hb[col[j]] (bf16 rows) --------
__global__ __launch_bounds__(256) void gather_kernel(const unsigned int* __restrict__ hb,
                                                     const int* __restrict__ rowptr,
                                                     const int* __restrict__ col,
                                                     float* __restrict__ agg) {
    const int lane = threadIdx.x & 63;
    const int n = blockIdx.x * 4 + __builtin_amdgcn_readfirstlane(threadIdx.x >> 6);
    if (n >= kN) return;
    const int e0 = rowptr[n], e1 = rowptr[n + 1];
    float2* __restrict__ op = reinterpret_cast<float2*>(agg);
    if (e0 == e1) {
        op[(size_t)n * 64 + lane] = make_float2(0.f, 0.f);
        return;
    }
    const int last = e1 - 1;
    float ax = 0.f, ay = 0.f, bx = 0.f, by = 0.f;
    float cx = 0.f, cy = 0.f, dx = 0.f, dy = 0.f;
    for (int e = e0; e < e1; e += 8) {
        int i0, i1, i2, i3, i4, i5, i6, i7;
        float m0, m1, m2, m3, m4, m5, m6, m7;
        {
            int t;
            t = e + 0; m0 = (t <= last) ? 1.f : 0.f; i0 = col[t <= last ? t : last];
            t = e + 1; m1 = (t <= last) ? 1.f : 0.f; i1 = col[t <= last ? t : last];
            t = e + 2; m2 = (t <= last) ? 1.f : 0.f; i2 = col[t <= last ? t : last];
            t = e + 3; m3 = (t <= last) ? 1.f : 0.f; i3 = col[t <= last ? t : last];
            t = e + 4; m4 = (t <= last) ? 1.f : 0.f; i4 = col[t <= last ? t : last];
            t = e + 5; m5 = (t <= last) ? 1.f : 0.f; i5 = col[t <= last ? t : last];
            t = e + 6; m6 = (t <= last) ? 1.f : 0.f; i6 = col[t <= last ? t : last];
            t = e + 7; m7 = (t <= last) ? 1.f : 0.f; i7 = col[t <= last ? t : last];
        }
        unsigned int u0 = hb[(size_t)i0 * 64 + lane];
        unsigned int u1 = hb[(size_t)i1 * 64 + lane];
        unsigned int u2 = hb[(size_t)i2 * 64 + lane];
        unsigned int u3 = hb[(size_t)i3 * 64 + lane];
        unsigned int u4 = hb[(size_t)i4 * 64 + lane];
        unsigned int u5 = hb[(size_t)i5 * 64 + lane];
        unsigned int u6 = hb[(size_t)i6 * 64 + lane];
        unsigned int u7 = hb[(size_t)i7 * 64 + lane];
        ax = fmaf(m0, bf2f(u0 & 0xffffu), ax); ay = fmaf(m0, bf2f(u0 >> 16), ay);
        bx = fmaf(m1, bf2f(u1 & 0xffffu), bx); by = fmaf(m1, bf2f(u1 >> 16), by);
        cx = fmaf(m2, bf2f(u2 & 0xffffu), cx); cy = fmaf(m2, bf2f(u2 >> 16), cy);
        dx = fmaf(m3, bf2f(u3 & 0xffffu), dx); dy = fmaf(m3, bf2f(u3 >> 16), dy);
        ax = fmaf(m4, bf2f(u4 & 0xffffu), ax); ay = fmaf(m4, bf2f(u4 >> 16), ay);
        bx = fmaf(m5, bf2f(u5 & 0xffffu), bx); by = fmaf(m5, bf2f(u5 >> 16), by);
        cx = fmaf(m6, bf2f(u6 & 0xffffu), cx); cy = fmaf(m6, bf2f(u6 >> 16), cy);
        dx = fmaf(m7, bf2f(u7 & 0xffffu), dx); dy = fmaf(m7, bf2f(u7 >> 16), dy);
    }
    op[(size_t)n * 64 + lane] = make_float2((ax + bx) + (cx + dx), (ay + by) + (cy + dy));
}

// ---------------- MFMA GEMM: one wave per 16-row tile, full 128 cols -------------
// MODE 0: A = (1+eps)*A0 + A1, relu->out
// MODE 1: A = A0,              relu->out, + per-block column sum/sumsq partials
// MODE 2: A = A0,              tanh->out
template <int MODE>
__global__ __launch_bounds__(256) void mfma_gemm(const float* __restrict__ A0,
                                                 const float* __restrict__ A1,
                                                 const short* __restrict__ wpk, int mat,
                                                 const float* __restrict__ bias,
                                                 const float* __restrict__ eps_p, int layer,
                                                 float* __restrict__ out,
                                                 float* __restrict__ spart) {
    const int lane = threadIdx.x & 63;
    const int wid = threadIdx.x >> 6;
    const int tile = blockIdx.x * 4 + wid;
    const bool valid = (tile * 16 < kN);
    if (MODE != 1 && !valid) return;
    const int row0 = tile * 16;
    const int m15 = lane & 15;
    const int kg = lane >> 4;  // 0..3
    const int arow = row0 + m15;

    float scale = 1.0f;
    if (MODE == 0) scale = 1.0f + eps_p[layer];

    const short8v* wp = reinterpret_cast<const short8v*>(wpk + (size_t)mat * 32768);

    f32x4 acc[8];
#pragma unroll
    for (int t = 0; t < 8; ++t) acc[t] = (f32x4)0.0f;

    if (valid) {
#pragma unroll
        for (int kc = 0; kc < 4; ++kc) {
            const float4* ap =
                reinterpret_cast<const float4*>(A0 + (size_t)arow * kH + kc * 32 + kg * 8);
            float4 v0 = ap[0], v1 = ap[1];
            float a[8] = {v0.x, v0.y, v0.z, v0.w, v1.x, v1.y, v1.z, v1.w};
            if (MODE == 0) {
                const float4* bp =
                    reinterpret_cast<const float4*>(A1 + (size_t)arow * kH + kc * 32 + kg * 8);
                float4 u0 = bp[0], u1 = bp[1];
                float u[8] = {u0.x, u0.y, u0.z, u0.w, u1.x, u1.y, u1.z, u1.w};
#pragma unroll
                for (int e = 0; e < 8; ++e) a[e] = scale * a[e] + u[e];
            }
            short8v ah, al;
#pragma unroll
            for (int e = 0; e < 8; ++e) {
                unsigned short h = f2bf(a[e]);
                ah[e] = (short)h;
                al[e] = (short)f2bf(a[e] - bf2f(h));
            }
#pragma unroll
            for (int t = 0; t < 8; ++t) {
                int f = (kc * 8 + t) * 64 + lane;
                short8v wh = wp[f];
                short8v wl = wp[2048 + f];
                acc[t] = __builtin_amdgcn_mfma_f32_16x16x32_bf16(al, wh, acc[t], 0, 0, 0);
                acc[t] = __builtin_amdgcn_mfma_f32_16x16x32_bf16(ah, wl, acc[t], 0, 0, 0);
                acc[t] = __builtin_amdgcn_mfma_f32_16x16x32_bf16(ah, wh, acc[t], 0, 0, 0);
            }
        }
    }

    __shared__ float sst[4][kH], sqt[4][kH];
    const int orow0 = row0 + kg * 4;
#pragma unroll
    for (int t = 0; t < 8; ++t) {
        int cl = t * 16 + m15;
        float b = bias[cl];
        float st = 0.f, qt = 0.f;
#pragma unroll
        for (int r = 0; r < 4; ++r) {
            float o = acc[t][r] + b;
            if (MODE < 2)
                o = fmaxf(o, 0.f);
            else
                o = tanhf(o);
            if (valid) out[(size_t)(orow0 + r) * kH + cl] = o;
            st += o;
            qt = fmaf(o, o, qt);
        }
        if (MODE == 1) {
            if (!valid) { st = 0.f; qt = 0.f; }
            st += __shfl_xor(st, 16); st += __shfl_xor(st, 32);
            qt += __shfl_xor(qt, 16); qt += __shfl_xor(qt, 32);
            if (kg == 0) { sst[wid][cl] = st; sqt[wid][cl] = qt; }
        }
    }
    if (MODE == 1) {
        __syncthreads();
        int c = threadIdx.x;
        float v;
        if (c < kH) v = sst[0][c] + sst[1][c] + sst[2][c] + sst[3][c];
        else { int cc = c - kH; v = sqt[0][cc] + sqt[1][cc] + sqt[2][cc] + sqt[3][cc]; }
        spart[(size_t)blockIdx.x * 256 + c] = v;
    }
}

// ---------------- fold per-block partials into stats (sums[128] | sumsq[128]) ----------
__global__ __launch_bounds__(256) void stats3_kernel(const float* __restrict__ spart,
                                                     float* __restrict__ stats) {
    const int c = threadIdx.x;  // 0..255
    float s = 0.f;
    for (int k = blockIdx.x; k < kGemmGrid; k += gridDim.x)
        s += spart[(size_t)k * 256 + c];
    atomicAdd(&stats[c], s);
}

// ---------------- two-phase segment mean pool ----------------
__global__ __launch_bounds__(256) void pool1_kernel(const float* __restrict__ y,
                                                    const int* __restrict__ gp,
                                                    float* __restrict__ partial) {
    const int g = blockIdx.x >> 4;
    const int s = blockIdx.x & 15;
    const int c = threadIdx.x & 127;
    const int q = threadIdx.x >> 7;  // 0..1
    const int rs = gp[g], re = gp[g + 1];
    float acc = 0.f;
    for (int r = rs + s * 2 + q; r < re; r += 32) acc += y[(size_t)r * kH + c];
    __shared__ float part[2][kH];
    part[q][c] = acc;
    __syncthreads();
    if (q == 0) partial[(size_t)blockIdx.x * kH + c] = part[0][c] + part[1][c];
}

__global__ void pool2_kernel(const float* __restrict__ partial, const int* __restrict__ gp,
                             float* __restrict__ out) {
    const int g = blockIdx.x;
    const int c = threadIdx.x;  // 128
    float v = 0.f;
#pragma unroll
    for (int s = 0; s < 16; ++s) v += partial[(size_t)((g << 4) + s) * kH + c];
    out[g * kH + c] = v / fmaxf((float)(gp[g + 1] - gp[g]), 1.0f);
}

// ---------------- BN (+ optional relu + residual) + bf16 mirror store ----------------
__global__ __launch_bounds__(256) void bn_kernel(const float* __restrict__ h2,
                                                 float* __restrict__ hcur,
                                                 unsigned int* __restrict__ hb,
                                                 const float* __restrict__ gamma,
                                                 const float* __restrict__ beta,
                                                 const float* __restrict__ sums,
                                                 const float* __restrict__ sumsq,
                                                 int first, int last) {
    const float invN = 1.0f / (float)kN;
    const size_t total = (size_t)kN * (kH / 4);
    const size_t stride = (size_t)gridDim.x * blockDim.x;
    for (size_t i = (size_t)blockIdx.x * blockDim.x + threadIdx.x; i < total; i += stride) {
        int c0 = ((int)(i & 31)) * 4;
        float4 s4 = *reinterpret_cast<const float4*>(sums + c0);
        float4 q4 = *reinterpret_cast<const float4*>(sumsq + c0);
        float4 g4 = *reinterpret_cast<const float4*>(gamma + c0);
        float4 be4 = *reinterpret_cast<const float4*>(beta + c0);
        float4 h4 = reinterpret_cast<const float4*>(h2)[i];
        float o0, o1, o2, o3;
        {
            float mu = s4.x * invN, var = fmaxf(q4.x * invN - mu * mu, 0.f);
            o0 = (h4.x - mu) * rsqrtf(var + kBnEps) * g4.x + be4.x;
        }
        {
            float mu = s4.y * invN, var = fmaxf(q4.y * invN - mu * mu, 0.f);
            o1 = (h4.y - mu) * rsqrtf(var + kBnEps) * g4.y + be4.y;
        }
        {
            float mu = s4.z * invN, var = fmaxf(q4.z * invN - mu * mu, 0.f);
            o2 = (h4.z - mu) * rsqrtf(var + kBnEps) * g4.z + be4.z;
        }
        {
            float mu = s4.w * invN, var = fmaxf(q4.w * invN - mu * mu, 0.f);
            o3 = (h4.w - mu) * rsqrtf(var + kBnEps) * g4.w + be4.w;
        }
        float4 r;
        if (first) {
            r = make_float4(o0, o1, o2, o3);
        } else {
            float4 p = reinterpret_cast<const float4*>(hcur)[i];
            r = make_float4(p.x + fmaxf(o0, 0.f), p.y + fmaxf(o1, 0.f),
                            p.z + fmaxf(o2, 0.f), p.w + fmaxf(o3, 0.f));
        }
        reinterpret_cast<float4*>(hcur)[i] = r;
        if (!last) {
            unsigned int p01 = (unsigned int)f2bf(r.x) | ((unsigned int)f2bf(r.y) << 16);
            unsigned int p23 = (unsigned int)f2bf(r.z) | ((unsigned int)f2bf(r.w) << 16);
            hb[i * 2] = p01;
            hb[i * 2 + 1] = p23;
        }
    }
}

// ---------------- launch ----------------
extern "C" void kernel_launch(void* const* d_in, const int* in_sizes, int n_in,
                              void* d_out, int out_size, void* d_ws, size_t ws_size,
                              hipStream_t stream) {
    const float* x     = (const float*)d_in[0];
    const int*   ei    = (const int*)d_in[1];
    const int*   batch = (const int*)d_in[2];
    const float* W1    = (const float*)d_in[3];
    const float* b1    = (const float*)d_in[4];
    const float* W2    = (const float*)d_in[5];
    const float* b2    = (const float*)d_in[6];
    const float* gamma = (const float*)d_in[7];
    const float* beta  = (const float*)d_in[8];
    const float* eps   = (const float*)d_in[9];
    const float* linW  = (const float*)d_in[10];
    const float* linb  = (const float*)d_in[11];
    float* out = (float*)d_out;

    char* ws = (char*)d_ws;
    size_t off = 0;
    auto alloc = [&](size_t bytes) -> char* {
        char* p = ws + off;
        off = (off + bytes + 15) & ~(size_t)15;
        return p;
    };
    float* agg    = (float*)alloc((size_t)kN * kH * 4);  // h2 after GEMM2; partial during pool
    float* hcur   = (float*)alloc((size_t)kN * kH * 4);
    float* hmid   = (float*)alloc((size_t)kN * kH * 4);  // also final tanh output y
    unsigned int* hb = (unsigned int*)alloc((size_t)kN * kH * 2);  // bf16 mirror
    int*   rowptr = (int*)alloc((size_t)(kN + 1) * 4);
    int*   colidx = (int*)alloc((size_t)kE * 4);
    unsigned int* part = (unsigned int*)alloc((size_t)kE * 4);  // packed (dst<<16)|src
    int*   bh_in  = (int*)alloc((size_t)kM * 4);
    int*   bh_loc = (int*)alloc((size_t)kM * 4);
    int*   bh_ex  = (int*)alloc((size_t)kM * 4);
    int*   sbp    = (int*)alloc((size_t)128 * 4);
    float* stats  = (float*)alloc((size_t)kL * 256 * 4);
    float* spart  = (float*)alloc((size_t)kGemmGrid * 256 * 4);
    int*   gp     = (int*)alloc((size_t)(kG + 1) * 4);
    short* wpk    = (short*)alloc((size_t)11 * 32768 * 2);

    float* partial = agg;  // [kG*16][kH], only live during pooling (agg free then)

    const int* srcp = ei;       // edge_index[0] (source)
    const int* dstp = ei + kE;  // edge_index[1] (target)

    hipMemsetAsync(stats, 0, (size_t)kL * 256 * 4, stream);

    const int scanBlocks = (kM + 511) / 512;  // 75
    part1a_kernel<<<kG1, 256, 0, stream>>>(dstp, bh_in);
    scanP1_kernel<<<scanBlocks, 512, 0, stream>>>(bh_in, bh_loc, sbp, kM);
    scanP2_kernel<<<1, 128, 0, stream>>>(sbp, scanBlocks);
    scanP3_kernel<<<scanBlocks, 512, 0, stream>>>(bh_loc, sbp, bh_ex, kM);
    part1b_kernel<<<kG1, 256, 0, stream>>>(srcp, dstp, bh_ex, part);
    bucket_kernel<<<kB, 1024, 0, stream>>>(part, bh_ex, rowptr, colidx);
    gp_kernel<<<(kN + 255) / 256, 256, 0, stream>>>(batch, gp);
    pack_kernel<<<11, 256, 0, stream>>>(W1, W2, linW, wpk);
    conv_kernel<<<(kN * (kH / 4) + 255) / 256, 256, 0, stream>>>(x, hb);

    for (int l = 0; l < kL; ++l) {
        const float* hin = (l == 0) ? x : hcur;
        gather_kernel<<<(kN + 3) / 4, 256, 0, stream>>>(hb, rowptr, colidx, agg);
        mfma_gemm<0><<<kGemmGrid, 256, 0, stream>>>(hin, agg, wpk, l, b1 + (size_t)l * kH,
                                                    eps, l, hmid, nullptr);
        mfma_gemm<1><<<kGemmGrid, 256, 0, stream>>>(hmid, nullptr, wpk, 5 + l,
                                                    b2 + (size_t)l * kH, nullptr, 0, agg,
                                                    spart);
        stats3_kernel<<<64, 256, 0, stream>>>(spart, stats + l * 256);
        bn_kernel<<<2048, 256, 0, stream>>>(agg, hcur, hb, gamma + (size_t)l * kH,
                                            beta + (size_t)l * kH, stats + l * 256,
                                            stats + l * 256 + 128, l == 0 ? 1 : 0,
                                            l == kL - 1 ? 1 : 0);
    }
    mfma_gemm<2><<<kGemmGrid, 256, 0, stream>>>(hcur, nullptr, wpk, 10, linb, nullptr, 0, hmid,
                                                nullptr);
    pool1_kernel<<<kG * 16, 256, 0, stream>>>(hmid, gp, partial);
    pool2_kernel<<<kG, kH, 0, stream>>>(partial, gp, out);
}